// Round 7
// baseline (1025.885 us; speedup 1.0000x reference)
//
#include <hip/hip_runtime.h>

#define N_NODES 50000
#define N_EDGES 300000
#define G_GRAPHS 1024
#define HID 256
#define NLAYERS 4

typedef unsigned short ushort_t;
typedef __attribute__((ext_vector_type(8))) short bf16x8;
typedef __attribute__((ext_vector_type(8))) unsigned short u16x8;
typedef __attribute__((ext_vector_type(4))) float f32x4;

__device__ __forceinline__ float bf2f(ushort_t u) {
  unsigned int x = ((unsigned int)u) << 16;
  return __builtin_bit_cast(float, x);
}
__device__ __forceinline__ ushort_t f2bf(float f) {
  unsigned int x = __builtin_bit_cast(unsigned int, f);
  unsigned int lsb = (x >> 16) & 1u;
  x += 0x7fffu + lsb;
  return (ushort_t)(x >> 16);
}

// h(bf16) = relu(x @ encW + encB)
__global__ __launch_bounds__(256) void k_encoder(const float* __restrict__ x,
    const float* __restrict__ W, const float* __restrict__ b,
    ushort_t* __restrict__ h, int n)
{
  int j = threadIdx.x;
  float wcol[11];
#pragma unroll
  for (int k = 0; k < 11; ++k) wcol[k] = W[k * HID + j];
  float bj = b[j];
  __shared__ float xs[8][11];
  int base = blockIdx.x * 8;
  if (j < 88) {
    int r = j / 11, k = j % 11;
    int row = base + r;
    if (row < n) xs[r][k] = x[row * 11 + k];
  }
  __syncthreads();
#pragma unroll
  for (int r = 0; r < 8; ++r) {
    int row = base + r;
    if (row >= n) break;
    float acc = bj;
#pragma unroll
    for (int k = 0; k < 11; ++k) acc += xs[r][k] * wcol[k];
    h[(size_t)row * HID + j] = f2bf(fmaxf(acc, 0.f));
  }
}

// ---- CSR build ----
__global__ __launch_bounds__(256) void k_hist(const int* __restrict__ dst,
    int* __restrict__ offs, int E)
{
  int e = blockIdx.x * 256 + threadIdx.x;
  if (e < E) atomicAdd(&offs[dst[e]], 1);
}

__global__ __launch_bounds__(1024) void k_scan(int* __restrict__ offs, int n)
{
  __shared__ int wsum[16];
  __shared__ int s_carry;
  int tid = threadIdx.x, lane = tid & 63, wid = tid >> 6;
  if (tid == 0) s_carry = 0;
  __syncthreads();
  for (int base = 0; base < n; base += 1024) {
    int idx = base + tid;
    int v = (idx < n) ? offs[idx] : 0;
    int x = v;
#pragma unroll
    for (int off = 1; off < 64; off <<= 1) {
      int t = __shfl_up(x, off);
      if (lane >= off) x += t;
    }
    if (lane == 63) wsum[wid] = x;
    __syncthreads();
    if (wid == 0 && lane < 16) {
      int w = wsum[lane];
#pragma unroll
      for (int off = 1; off < 16; off <<= 1) {
        int t = __shfl_up(w, off);
        if (lane >= off) w += t;
      }
      wsum[lane] = w;
    }
    __syncthreads();
    int wbase = (wid == 0) ? 0 : wsum[wid - 1];
    int excl = s_carry + wbase + x - v;
    int total = wsum[15];
    __syncthreads();
    if (idx < n) offs[idx] = excl;
    if (tid == 0) s_carry += total;
    __syncthreads();
  }
  if (tid == 0) offs[n] = s_carry;
}

__global__ __launch_bounds__(256) void k_fill(const int* __restrict__ src,
    const int* __restrict__ dst, int* __restrict__ offs,
    int2* __restrict__ epair, int E)
{
  int e = blockIdx.x * 256 + threadIdx.x;
  if (e < E) {
    int d = dst[e];
    int p = atomicAdd(&offs[d], 1);
    epair[p] = make_int2(e, src[e]);
  }
}

// W [256][256] f32 -> Wt [n][k] bf16 (transposed), nmats via grid.y
__global__ __launch_bounds__(256) void k_prep(const float* __restrict__ W,
    ushort_t* __restrict__ Wt)
{
  __shared__ float ld[16][257];
  int mat = blockIdx.y;
  int k0 = blockIdx.x * 16;
  const float* Wm = W + (size_t)mat * HID * HID;
  ushort_t* Wtm = Wt + (size_t)mat * HID * HID;
  int tid = threadIdx.x;
#pragma unroll
  for (int i = 0; i < 16; ++i) ld[i][tid] = Wm[(size_t)(k0 + i) * HID + tid];
  __syncthreads();
#pragma unroll
  for (int v = 0; v < 4; ++v) {
    ushort4 u = make_ushort4(f2bf(ld[v*4+0][tid]), f2bf(ld[v*4+1][tid]),
                             f2bf(ld[v*4+2][tid]), f2bf(ld[v*4+3][tid]));
    *(ushort4*)&Wtm[(size_t)tid * HID + k0 + v * 4] = u;
  }
}

// one wave per node, pairwise-pipelined over in-edges:
// zin[i] = h[i] + sum relu(h[src] + ea@eW + eb)
__global__ __launch_bounds__(256) void k_gather(const ushort_t* __restrict__ h,
    const float* __restrict__ ea, const int* __restrict__ offs,
    const int2* __restrict__ epair, const float* __restrict__ eW,
    const float* __restrict__ eb, ushort_t* __restrict__ zin, int n)
{
  int tid = threadIdx.x;
  int wave = tid >> 6, lane = tid & 63;
  int node = blockIdx.x * 4 + wave;
  int c4 = lane * 4;
  float4 w0 = *(const float4*)&eW[0 * HID + c4];
  float4 w1 = *(const float4*)&eW[1 * HID + c4];
  float4 w2 = *(const float4*)&eW[2 * HID + c4];
  float4 w3 = *(const float4*)&eW[3 * HID + c4];
  float4 w4 = *(const float4*)&eW[4 * HID + c4];
  float4 bi = *(const float4*)&eb[c4];
  if (node >= n) return;
  int lo = (node == 0) ? 0 : offs[node - 1];
  int hi = offs[node];
  ushort4 ho = *(const ushort4*)&h[(size_t)node * HID + c4];
  float ax = bf2f(ho.x), ay = bf2f(ho.y), az = bf2f(ho.z), aw = bf2f(ho.w);
  int p = lo;
  // pairwise: both edges' loads issue before compute (2x MLP)
  for (; p + 1 < hi; p += 2) {
    int2 pa = epair[p], pb = epair[p + 1];
    const float* eA = ea + (size_t)pa.x * 5;
    const float* eB = ea + (size_t)pb.x * 5;
    float a0 = eA[0], a1 = eA[1], a2 = eA[2], a3 = eA[3], a4 = eA[4];
    float b0 = eB[0], b1 = eB[1], b2 = eB[2], b3 = eB[3], b4 = eB[4];
    ushort4 hA = *(const ushort4*)&h[(size_t)pa.y * HID + c4];
    ushort4 hB = *(const ushort4*)&h[(size_t)pb.y * HID + c4];
    float m0 = bi.x, m1 = bi.y, m2 = bi.z, m3 = bi.w;
    m0 = fmaf(a0, w0.x, m0); m1 = fmaf(a0, w0.y, m1); m2 = fmaf(a0, w0.z, m2); m3 = fmaf(a0, w0.w, m3);
    m0 = fmaf(a1, w1.x, m0); m1 = fmaf(a1, w1.y, m1); m2 = fmaf(a1, w1.z, m2); m3 = fmaf(a1, w1.w, m3);
    m0 = fmaf(a2, w2.x, m0); m1 = fmaf(a2, w2.y, m1); m2 = fmaf(a2, w2.z, m2); m3 = fmaf(a2, w2.w, m3);
    m0 = fmaf(a3, w3.x, m0); m1 = fmaf(a3, w3.y, m1); m2 = fmaf(a3, w3.z, m2); m3 = fmaf(a3, w3.w, m3);
    m0 = fmaf(a4, w4.x, m0); m1 = fmaf(a4, w4.y, m1); m2 = fmaf(a4, w4.z, m2); m3 = fmaf(a4, w4.w, m3);
    m0 += bf2f(hA.x); m1 += bf2f(hA.y); m2 += bf2f(hA.z); m3 += bf2f(hA.w);
    ax += fmaxf(m0, 0.f); ay += fmaxf(m1, 0.f); az += fmaxf(m2, 0.f); aw += fmaxf(m3, 0.f);
    float n0 = bi.x, n1 = bi.y, n2 = bi.z, n3 = bi.w;
    n0 = fmaf(b0, w0.x, n0); n1 = fmaf(b0, w0.y, n1); n2 = fmaf(b0, w0.z, n2); n3 = fmaf(b0, w0.w, n3);
    n0 = fmaf(b1, w1.x, n0); n1 = fmaf(b1, w1.y, n1); n2 = fmaf(b1, w1.z, n2); n3 = fmaf(b1, w1.w, n3);
    n0 = fmaf(b2, w2.x, n0); n1 = fmaf(b2, w2.y, n1); n2 = fmaf(b2, w2.z, n2); n3 = fmaf(b2, w2.w, n3);
    n0 = fmaf(b3, w3.x, n0); n1 = fmaf(b3, w3.y, n1); n2 = fmaf(b3, w3.z, n2); n3 = fmaf(b3, w3.w, n3);
    n0 = fmaf(b4, w4.x, n0); n1 = fmaf(b4, w4.y, n1); n2 = fmaf(b4, w4.z, n2); n3 = fmaf(b4, w4.w, n3);
    n0 += bf2f(hB.x); n1 += bf2f(hB.y); n2 += bf2f(hB.z); n3 += bf2f(hB.w);
    ax += fmaxf(n0, 0.f); ay += fmaxf(n1, 0.f); az += fmaxf(n2, 0.f); aw += fmaxf(n3, 0.f);
  }
  if (p < hi) {
    int2 pa = epair[p];
    const float* eA = ea + (size_t)pa.x * 5;
    float a0 = eA[0], a1 = eA[1], a2 = eA[2], a3 = eA[3], a4 = eA[4];
    ushort4 hA = *(const ushort4*)&h[(size_t)pa.y * HID + c4];
    float m0 = bi.x, m1 = bi.y, m2 = bi.z, m3 = bi.w;
    m0 = fmaf(a0, w0.x, m0); m1 = fmaf(a0, w0.y, m1); m2 = fmaf(a0, w0.z, m2); m3 = fmaf(a0, w0.w, m3);
    m0 = fmaf(a1, w1.x, m0); m1 = fmaf(a1, w1.y, m1); m2 = fmaf(a1, w1.z, m2); m3 = fmaf(a1, w1.w, m3);
    m0 = fmaf(a2, w2.x, m0); m1 = fmaf(a2, w2.y, m1); m2 = fmaf(a2, w2.z, m2); m3 = fmaf(a2, w2.w, m3);
    m0 = fmaf(a3, w3.x, m0); m1 = fmaf(a3, w3.y, m1); m2 = fmaf(a3, w3.z, m2); m3 = fmaf(a3, w3.w, m3);
    m0 = fmaf(a4, w4.x, m0); m1 = fmaf(a4, w4.y, m1); m2 = fmaf(a4, w4.z, m2); m3 = fmaf(a4, w4.w, m3);
    m0 += bf2f(hA.x); m1 += bf2f(hA.y); m2 += bf2f(hA.z); m3 += bf2f(hA.w);
    ax += fmaxf(m0, 0.f); ay += fmaxf(m1, 0.f); az += fmaxf(m2, 0.f); aw += fmaxf(m3, 0.f);
  }
  *(ushort4*)&zin[(size_t)node * HID + c4] =
      make_ushort4(f2bf(ax), f2bf(ay), f2bf(az), f2bf(aw));
}

// Weights-in-LDS MFMA GEMM: out(bf16)[M,256] = A(bf16)[M,256] @ Wt^T + bias.
// Wt [n][k] bf16. LDS holds a 128-col half of Wt in MFMA B-frag layout:
// frag f = ct*8+kt (1 KB each), lane l's 16B at f*1024 + l*16 -> ds_read_b128
// at lane*16 is conflict-free. Persistent blocks grid-stride over 16-row tiles.
template<int DO_RELU, int STATS>
__global__ __launch_bounds__(256, 2) void k_gemm_lds(const ushort_t* __restrict__ A,
    const ushort_t* __restrict__ Wt, const float* __restrict__ bias,
    ushort_t* __restrict__ out, float* __restrict__ stats, int M)
{
  __shared__ ushort_t Ws[32768];  // exactly 64 KB
  int tid = threadIdx.x;
  int wave = tid >> 6, lane = tid & 63;
  int m = lane & 15, quad = lane >> 4;
  int col0 = blockIdx.y * 128;
  for (int c = tid; c < 4096; c += 256) {
    int f = c >> 6, l = c & 63;
    int ct = f >> 3, kt = f & 7;
    int n = col0 + ct * 16 + (l & 15);
    int k = kt * 32 + (l >> 4) * 8;
    *(u16x8*)&Ws[f * 512 + l * 8] = *(const u16x8*)(Wt + (size_t)n * HID + k);
  }
  __syncthreads();
  float bv[8];
#pragma unroll
  for (int ct = 0; ct < 8; ++ct) bv[ct] = bias[col0 + ct * 16 + m];
  int ntiles = M >> 4;  // M % 16 == 0
  for (int t = blockIdx.x * 4 + wave; t < ntiles; t += gridDim.x * 4) {
    int row0 = t << 4;
    const ushort_t* Ap = A + (size_t)(row0 + m) * HID + quad * 8;
    bf16x8 af[8];
#pragma unroll
    for (int kt = 0; kt < 8; ++kt) af[kt] = *(const bf16x8*)(Ap + kt * 32);
    f32x4 acc[8];
#pragma unroll
    for (int ct = 0; ct < 8; ++ct) acc[ct] = (f32x4){0.f, 0.f, 0.f, 0.f};
#pragma unroll
    for (int kt = 0; kt < 8; ++kt) {
#pragma unroll
      for (int ct = 0; ct < 8; ++ct) {
        bf16x8 b = *(const bf16x8*)&Ws[(ct * 8 + kt) * 512 + lane * 8];
        acc[ct] = __builtin_amdgcn_mfma_f32_16x16x32_bf16(af[kt], b, acc[ct], 0, 0, 0);
      }
    }
#pragma unroll
    for (int ct = 0; ct < 8; ++ct) {
      int col = col0 + ct * 16 + m;
      float ssum = 0.f, ssq = 0.f;
#pragma unroll
      for (int reg = 0; reg < 4; ++reg) {
        float o = acc[ct][reg] + bv[ct];
        if (DO_RELU) o = fmaxf(o, 0.f);
        out[(size_t)(row0 + quad * 4 + reg) * HID + col] = f2bf(o);
        if (STATS) { ssum += o; ssq = fmaf(o, o, ssq); }
      }
      if (STATS) {
        ssum += __shfl_xor(ssum, 16); ssum += __shfl_xor(ssum, 32);
        ssq  += __shfl_xor(ssq, 16);  ssq  += __shfl_xor(ssq, 32);
        if (quad == 0) {
          unsafeAtomicAdd(&stats[col], ssum);
          unsafeAtomicAdd(&stats[HID + col], ssq);
        }
      }
    }
  }
}

// also re-zeros stats for the next layer (single memset before the loop)
__global__ void k_bn_finalize(float* __restrict__ stats,
    const float* __restrict__ g, const float* __restrict__ b,
    float* __restrict__ ss, int n)
{
  int j = threadIdx.x;
  float inv_n = 1.f / (float)n;
  float mu = stats[j] * inv_n;
  float var = stats[HID + j] * inv_n - mu * mu;
  float rs = rsqrtf(var + 1e-5f);
  float sc = g[j] * rs;
  ss[j] = sc;
  ss[HID + j] = b[j] - mu * sc;
  stats[j] = 0.f;
  stats[HID + j] = 0.f;
}

// h(bf16) = relu(z*scale + shift) + h ; z bf16
__global__ __launch_bounds__(256) void k_bn_apply(const ushort_t* __restrict__ z,
    const float* __restrict__ ss, ushort_t* __restrict__ h, int total4)
{
  int idx = blockIdx.x * 256 + threadIdx.x;
  if (idx >= total4) return;
  int col = (idx & 63) * 4;
  ushort4 zv = *(const ushort4*)(z + (size_t)idx * 4);
  ushort4 hv = *(const ushort4*)(h + (size_t)idx * 4);
  float o0 = fmaxf(fmaf(bf2f(zv.x), ss[col + 0], ss[HID + col + 0]), 0.f) + bf2f(hv.x);
  float o1 = fmaxf(fmaf(bf2f(zv.y), ss[col + 1], ss[HID + col + 1]), 0.f) + bf2f(hv.y);
  float o2 = fmaxf(fmaf(bf2f(zv.z), ss[col + 2], ss[HID + col + 2]), 0.f) + bf2f(hv.z);
  float o3 = fmaxf(fmaf(bf2f(zv.w), ss[col + 3], ss[HID + col + 3]), 0.f) + bf2f(hv.w);
  *(ushort4*)(h + (size_t)idx * 4) = make_ushort4(f2bf(o0), f2bf(o1), f2bf(o2), f2bf(o3));
}

__device__ __forceinline__ int lbound(const int* __restrict__ b, int n, int key) {
  int lo = 0, hi = n;
  while (lo < hi) {
    int mid = (lo + hi) >> 1;
    if (b[mid] < key) lo = mid + 1; else hi = mid;
  }
  return lo;
}

// fused pool (batch sorted) + head MLP
__global__ __launch_bounds__(256) void k_head(const ushort_t* __restrict__ h,
    const int* __restrict__ batch,
    const float* __restrict__ W1, const float* __restrict__ b1,
    const float* __restrict__ W2, const float* __restrict__ b2,
    const float* __restrict__ W3, const float* __restrict__ b3,
    float* __restrict__ out)
{
  __shared__ float gf[3 * HID];
  __shared__ float g1[HID];
  __shared__ float red[4];
  int g = blockIdx.x, j = threadIdx.x;
  int lo = lbound(batch, N_NODES, g);
  int hi = lbound(batch, N_NODES, g + 1);
  float s = 0.f, mx = 0.f;  // h >= 0 by construction
  int i = lo;
  for (; i + 1 < hi; i += 2) {
    float v0 = bf2f(h[(size_t)i * HID + j]);
    float v1 = bf2f(h[(size_t)(i + 1) * HID + j]);
    s += v0 + v1; mx = fmaxf(mx, fmaxf(v0, v1));
  }
  if (i < hi) {
    float v = bf2f(h[(size_t)i * HID + j]);
    s += v; mx = fmaxf(mx, v);
  }
  float cntv = fmaxf((float)(hi - lo), 1.f);
  gf[j] = s / cntv;
  gf[HID + j] = s;
  gf[2 * HID + j] = mx;
  __syncthreads();
  float a0 = 0.f, a1 = 0.f, a2 = 0.f, a3 = 0.f;
  for (int k = 0; k < 3 * HID; k += 4) {
    a0 = fmaf(gf[k + 0], W1[(size_t)(k + 0) * HID + j], a0);
    a1 = fmaf(gf[k + 1], W1[(size_t)(k + 1) * HID + j], a1);
    a2 = fmaf(gf[k + 2], W1[(size_t)(k + 2) * HID + j], a2);
    a3 = fmaf(gf[k + 3], W1[(size_t)(k + 3) * HID + j], a3);
  }
  g1[j] = fmaxf(b1[j] + (a0 + a1) + (a2 + a3), 0.f);
  __syncthreads();
  float p = 0.f;
  if (j < 128) {
    float c0 = 0.f, c1 = 0.f, c2 = 0.f, c3 = 0.f;
    for (int k = 0; k < HID; k += 4) {
      c0 = fmaf(g1[k + 0], W2[(size_t)(k + 0) * 128 + j], c0);
      c1 = fmaf(g1[k + 1], W2[(size_t)(k + 1) * 128 + j], c1);
      c2 = fmaf(g1[k + 2], W2[(size_t)(k + 2) * 128 + j], c2);
      c3 = fmaf(g1[k + 3], W2[(size_t)(k + 3) * 128 + j], c3);
    }
    p = fmaxf(b2[j] + (c0 + c1) + (c2 + c3), 0.f) * W3[j];
  }
#pragma unroll
  for (int off = 32; off > 0; off >>= 1) p += __shfl_down(p, off);
  if ((j & 63) == 0) red[j >> 6] = p;
  __syncthreads();
  if (j == 0) out[g] = red[0] + red[1] + b3[0];
}

extern "C" void kernel_launch(void* const* d_in, const int* in_sizes, int n_in,
                              void* d_out, int out_size, void* d_ws, size_t ws_size,
                              hipStream_t stream)
{
  const float* x     = (const float*)d_in[0];
  const int*   ei    = (const int*)d_in[1];
  const float* ea    = (const float*)d_in[2];
  const int*   batch = (const int*)d_in[3];
  const float* encW  = (const float*)d_in[4];
  const float* encB  = (const float*)d_in[5];
  const float* edgeW = (const float*)d_in[6];
  const float* edgeB = (const float*)d_in[7];
  const float* W1    = (const float*)d_in[8];
  const float* b1    = (const float*)d_in[9];
  const float* W2    = (const float*)d_in[10];
  const float* b2    = (const float*)d_in[11];
  const float* bng   = (const float*)d_in[12];
  const float* bnb   = (const float*)d_in[13];
  const float* hW1   = (const float*)d_in[14];
  const float* hb1   = (const float*)d_in[15];
  const float* hW2   = (const float*)d_in[16];
  const float* hb2   = (const float*)d_in[17];
  const float* hW3   = (const float*)d_in[18];
  const float* hb3   = (const float*)d_in[19];
  float* out = (float*)d_out;

  const size_t NH = (size_t)N_NODES * HID;
  char* base = (char*)d_ws;
  auto alloc = [&](size_t bytes) -> char* {
    char* p = base; base += (bytes + 63) & ~(size_t)63; return p;
  };
  float*    stats = (float*)alloc(512 * 4);
  float*    ss    = (float*)alloc(512 * 4);
  int*      offs  = (int*)alloc(50001 * 4);
  int2*     epair = (int2*)alloc((size_t)N_EDGES * 8);
  ushort_t* Wt1   = (ushort_t*)alloc((size_t)NLAYERS * HID * HID * 2);
  ushort_t* Wt2   = (ushort_t*)alloc((size_t)NLAYERS * HID * HID * 2);
  ushort_t* zin   = (ushort_t*)alloc(NH * 2);  // also reused as z2
  ushort_t* z1    = (ushort_t*)alloc(NH * 2);
  ushort_t* h     = (ushort_t*)alloc(NH * 2);
  // total ~80.5 MB

  const int* src = ei;
  const int* dst = ei + N_EDGES;

  // CSR build + weight prep + stats zero (once per call)
  hipMemsetAsync(offs, 0, 50001 * sizeof(int), stream);
  hipMemsetAsync(stats, 0, 512 * sizeof(float), stream);
  k_hist<<<(N_EDGES + 255) / 256, 256, 0, stream>>>(dst, offs, N_EDGES);
  k_scan<<<1, 1024, 0, stream>>>(offs, N_NODES);
  k_fill<<<(N_EDGES + 255) / 256, 256, 0, stream>>>(src, dst, offs, epair, N_EDGES);
  k_prep<<<dim3(16, NLAYERS), 256, 0, stream>>>(W1, Wt1);
  k_prep<<<dim3(16, NLAYERS), 256, 0, stream>>>(W2, Wt2);

  k_encoder<<<(N_NODES + 7) / 8, 256, 0, stream>>>(x, encW, encB, h, N_NODES);

  const dim3 GGRID(128, 2);  // 256 persistent blocks, 2 col-halves
  for (int l = 0; l < NLAYERS; ++l) {
    k_gather<<<N_NODES / 4, 256, 0, stream>>>(
        h, ea, offs, epair, edgeW + (size_t)l * 5 * HID, edgeB + (size_t)l * HID,
        zin, N_NODES);
    // z1 = relu(zin @ W1 + b1)
    k_gemm_lds<1, 0><<<GGRID, 256, 0, stream>>>(
        zin, Wt1 + (size_t)l * HID * HID, b1 + (size_t)l * HID, z1, nullptr, N_NODES);
    // z2 = z1 @ W2 + b2 (into zin), fused column stats
    k_gemm_lds<0, 1><<<GGRID, 256, 0, stream>>>(
        z1, Wt2 + (size_t)l * HID * HID, b2 + (size_t)l * HID, zin, stats, N_NODES);
    k_bn_finalize<<<1, 256, 0, stream>>>(stats, bng + (size_t)l * HID,
                                         bnb + (size_t)l * HID, ss, N_NODES);
    k_bn_apply<<<(N_NODES * HID / 4 + 255) / 256, 256, 0, stream>>>(
        zin, ss, h, N_NODES * HID / 4);
  }

  k_head<<<G_GRAPHS, 256, 0, stream>>>(h, batch, hW1, hb1, hW2, hb2, hW3, hb3, out);
}

// Round 8
// 825.421 us; speedup vs baseline: 1.2429x; 1.2429x over previous
//
#include <hip/hip_runtime.h>

#define N_NODES 50000
#define N_EDGES 300000
#define G_GRAPHS 1024
#define HID 256
#define NLAYERS 4

typedef unsigned short ushort_t;
typedef __attribute__((ext_vector_type(8))) short bf16x8;
typedef __attribute__((ext_vector_type(8))) unsigned short u16x8;
typedef __attribute__((ext_vector_type(4))) float f32x4;

__device__ __forceinline__ float bf2f(ushort_t u) {
  unsigned int x = ((unsigned int)u) << 16;
  return __builtin_bit_cast(float, x);
}
__device__ __forceinline__ ushort_t f2bf(float f) {
  unsigned int x = __builtin_bit_cast(unsigned int, f);
  unsigned int lsb = (x >> 16) & 1u;
  x += 0x7fffu + lsb;
  return (ushort_t)(x >> 16);
}

// h(bf16) = relu(x @ encW + encB)
__global__ __launch_bounds__(256) void k_encoder(const float* __restrict__ x,
    const float* __restrict__ W, const float* __restrict__ b,
    ushort_t* __restrict__ h, int n)
{
  int j = threadIdx.x;
  float wcol[11];
#pragma unroll
  for (int k = 0; k < 11; ++k) wcol[k] = W[k * HID + j];
  float bj = b[j];
  __shared__ float xs[8][11];
  int base = blockIdx.x * 8;
  if (j < 88) {
    int r = j / 11, k = j % 11;
    int row = base + r;
    if (row < n) xs[r][k] = x[row * 11 + k];
  }
  __syncthreads();
#pragma unroll
  for (int r = 0; r < 8; ++r) {
    int row = base + r;
    if (row >= n) break;
    float acc = bj;
#pragma unroll
    for (int k = 0; k < 11; ++k) acc += xs[r][k] * wcol[k];
    h[(size_t)row * HID + j] = f2bf(fmaxf(acc, 0.f));
  }
}

// ---- CSR build ----
__global__ __launch_bounds__(256) void k_hist(const int* __restrict__ dst,
    int* __restrict__ offs, int E)
{
  int e = blockIdx.x * 256 + threadIdx.x;
  if (e < E) atomicAdd(&offs[dst[e]], 1);
}

__global__ __launch_bounds__(1024) void k_scan(int* __restrict__ offs, int n)
{
  __shared__ int wsum[16];
  __shared__ int s_carry;
  int tid = threadIdx.x, lane = tid & 63, wid = tid >> 6;
  if (tid == 0) s_carry = 0;
  __syncthreads();
  for (int base = 0; base < n; base += 1024) {
    int idx = base + tid;
    int v = (idx < n) ? offs[idx] : 0;
    int x = v;
#pragma unroll
    for (int off = 1; off < 64; off <<= 1) {
      int t = __shfl_up(x, off);
      if (lane >= off) x += t;
    }
    if (lane == 63) wsum[wid] = x;
    __syncthreads();
    if (wid == 0 && lane < 16) {
      int w = wsum[lane];
#pragma unroll
      for (int off = 1; off < 16; off <<= 1) {
        int t = __shfl_up(w, off);
        if (lane >= off) w += t;
      }
      wsum[lane] = w;
    }
    __syncthreads();
    int wbase = (wid == 0) ? 0 : wsum[wid - 1];
    int excl = s_carry + wbase + x - v;
    int total = wsum[15];
    __syncthreads();
    if (idx < n) offs[idx] = excl;
    if (tid == 0) s_carry += total;
    __syncthreads();
  }
  if (tid == 0) offs[n] = s_carry;
}

__global__ __launch_bounds__(256) void k_fill(const int* __restrict__ src,
    const int* __restrict__ dst, int* __restrict__ offs,
    int2* __restrict__ epair, int E)
{
  int e = blockIdx.x * 256 + threadIdx.x;
  if (e < E) {
    int d = dst[e];
    int p = atomicAdd(&offs[d], 1);
    epair[p] = make_int2(e, src[e]);
  }
}

// W [256][256] f32 -> Wt [n][k] bf16 (transposed), nmats via grid.y
__global__ __launch_bounds__(256) void k_prep(const float* __restrict__ W,
    ushort_t* __restrict__ Wt)
{
  __shared__ float ld[16][257];
  int mat = blockIdx.y;
  int k0 = blockIdx.x * 16;
  const float* Wm = W + (size_t)mat * HID * HID;
  ushort_t* Wtm = Wt + (size_t)mat * HID * HID;
  int tid = threadIdx.x;
#pragma unroll
  for (int i = 0; i < 16; ++i) ld[i][tid] = Wm[(size_t)(k0 + i) * HID + tid];
  __syncthreads();
#pragma unroll
  for (int v = 0; v < 4; ++v) {
    ushort4 u = make_ushort4(f2bf(ld[v*4+0][tid]), f2bf(ld[v*4+1][tid]),
                             f2bf(ld[v*4+2][tid]), f2bf(ld[v*4+3][tid]));
    *(ushort4*)&Wtm[(size_t)tid * HID + k0 + v * 4] = u;
  }
}

// one wave per node, pairwise-pipelined over in-edges:
// zin[i] = h[i] + sum relu(h[src] + ea@eW + eb)
__global__ __launch_bounds__(256) void k_gather(const ushort_t* __restrict__ h,
    const float* __restrict__ ea, const int* __restrict__ offs,
    const int2* __restrict__ epair, const float* __restrict__ eW,
    const float* __restrict__ eb, ushort_t* __restrict__ zin, int n)
{
  int tid = threadIdx.x;
  int wave = tid >> 6, lane = tid & 63;
  int node = blockIdx.x * 4 + wave;
  int c4 = lane * 4;
  float4 w0 = *(const float4*)&eW[0 * HID + c4];
  float4 w1 = *(const float4*)&eW[1 * HID + c4];
  float4 w2 = *(const float4*)&eW[2 * HID + c4];
  float4 w3 = *(const float4*)&eW[3 * HID + c4];
  float4 w4 = *(const float4*)&eW[4 * HID + c4];
  float4 bi = *(const float4*)&eb[c4];
  if (node >= n) return;
  int lo = (node == 0) ? 0 : offs[node - 1];
  int hi = offs[node];
  ushort4 ho = *(const ushort4*)&h[(size_t)node * HID + c4];
  float ax = bf2f(ho.x), ay = bf2f(ho.y), az = bf2f(ho.z), aw = bf2f(ho.w);
  int p = lo;
  for (; p + 1 < hi; p += 2) {
    int2 pa = epair[p], pb = epair[p + 1];
    const float* eA = ea + (size_t)pa.x * 5;
    const float* eB = ea + (size_t)pb.x * 5;
    float a0 = eA[0], a1 = eA[1], a2 = eA[2], a3 = eA[3], a4 = eA[4];
    float b0 = eB[0], b1 = eB[1], b2 = eB[2], b3 = eB[3], b4 = eB[4];
    ushort4 hA = *(const ushort4*)&h[(size_t)pa.y * HID + c4];
    ushort4 hB = *(const ushort4*)&h[(size_t)pb.y * HID + c4];
    float m0 = bi.x, m1 = bi.y, m2 = bi.z, m3 = bi.w;
    m0 = fmaf(a0, w0.x, m0); m1 = fmaf(a0, w0.y, m1); m2 = fmaf(a0, w0.z, m2); m3 = fmaf(a0, w0.w, m3);
    m0 = fmaf(a1, w1.x, m0); m1 = fmaf(a1, w1.y, m1); m2 = fmaf(a1, w1.z, m2); m3 = fmaf(a1, w1.w, m3);
    m0 = fmaf(a2, w2.x, m0); m1 = fmaf(a2, w2.y, m1); m2 = fmaf(a2, w2.z, m2); m3 = fmaf(a2, w2.w, m3);
    m0 = fmaf(a3, w3.x, m0); m1 = fmaf(a3, w3.y, m1); m2 = fmaf(a3, w3.z, m2); m3 = fmaf(a3, w3.w, m3);
    m0 = fmaf(a4, w4.x, m0); m1 = fmaf(a4, w4.y, m1); m2 = fmaf(a4, w4.z, m2); m3 = fmaf(a4, w4.w, m3);
    m0 += bf2f(hA.x); m1 += bf2f(hA.y); m2 += bf2f(hA.z); m3 += bf2f(hA.w);
    ax += fmaxf(m0, 0.f); ay += fmaxf(m1, 0.f); az += fmaxf(m2, 0.f); aw += fmaxf(m3, 0.f);
    float n0 = bi.x, n1 = bi.y, n2 = bi.z, n3 = bi.w;
    n0 = fmaf(b0, w0.x, n0); n1 = fmaf(b0, w0.y, n1); n2 = fmaf(b0, w0.z, n2); n3 = fmaf(b0, w0.w, n3);
    n0 = fmaf(b1, w1.x, n0); n1 = fmaf(b1, w1.y, n1); n2 = fmaf(b1, w1.z, n2); n3 = fmaf(b1, w1.w, n3);
    n0 = fmaf(b2, w2.x, n0); n1 = fmaf(b2, w2.y, n1); n2 = fmaf(b2, w2.z, n2); n3 = fmaf(b2, w2.w, n3);
    n0 = fmaf(b3, w3.x, n0); n1 = fmaf(b3, w3.y, n1); n2 = fmaf(b3, w3.z, n2); n3 = fmaf(b3, w3.w, n3);
    n0 = fmaf(b4, w4.x, n0); n1 = fmaf(b4, w4.y, n1); n2 = fmaf(b4, w4.z, n2); n3 = fmaf(b4, w4.w, n3);
    n0 += bf2f(hB.x); n1 += bf2f(hB.y); n2 += bf2f(hB.z); n3 += bf2f(hB.w);
    ax += fmaxf(n0, 0.f); ay += fmaxf(n1, 0.f); az += fmaxf(n2, 0.f); aw += fmaxf(n3, 0.f);
  }
  if (p < hi) {
    int2 pa = epair[p];
    const float* eA = ea + (size_t)pa.x * 5;
    float a0 = eA[0], a1 = eA[1], a2 = eA[2], a3 = eA[3], a4 = eA[4];
    ushort4 hA = *(const ushort4*)&h[(size_t)pa.y * HID + c4];
    float m0 = bi.x, m1 = bi.y, m2 = bi.z, m3 = bi.w;
    m0 = fmaf(a0, w0.x, m0); m1 = fmaf(a0, w0.y, m1); m2 = fmaf(a0, w0.z, m2); m3 = fmaf(a0, w0.w, m3);
    m0 = fmaf(a1, w1.x, m0); m1 = fmaf(a1, w1.y, m1); m2 = fmaf(a1, w1.z, m2); m3 = fmaf(a1, w1.w, m3);
    m0 = fmaf(a2, w2.x, m0); m1 = fmaf(a2, w2.y, m1); m2 = fmaf(a2, w2.z, m2); m3 = fmaf(a2, w2.w, m3);
    m0 = fmaf(a3, w3.x, m0); m1 = fmaf(a3, w3.y, m1); m2 = fmaf(a3, w3.z, m2); m3 = fmaf(a3, w3.w, m3);
    m0 = fmaf(a4, w4.x, m0); m1 = fmaf(a4, w4.y, m1); m2 = fmaf(a4, w4.z, m2); m3 = fmaf(a4, w4.w, m3);
    m0 += bf2f(hA.x); m1 += bf2f(hA.y); m2 += bf2f(hA.z); m3 += bf2f(hA.w);
    ax += fmaxf(m0, 0.f); ay += fmaxf(m1, 0.f); az += fmaxf(m2, 0.f); aw += fmaxf(m3, 0.f);
  }
  *(ushort4*)&zin[(size_t)node * HID + c4] =
      make_ushort4(f2bf(ax), f2bf(ay), f2bf(az), f2bf(aw));
}

// B-in-registers MFMA GEMM: out(bf16)[M,256] = A(bf16)[M,256] @ Wt^T + bias.
// Wt [n][k] bf16. Each wave owns a 32-col group x full K in registers
// (16 B-frags = 64 VGPRs, loaded once), then grid-strides over 16-row
// A-tiles: 8 global A-frag loads + 16 MFMAs per tile. No LDS, no barriers.
// STATS accumulates per-wave column partials in regs; one flush at end.
template<int DO_RELU, int STATS>
__global__ __launch_bounds__(256, 3) void k_gemm_breg(const ushort_t* __restrict__ A,
    const ushort_t* __restrict__ Wt, const float* __restrict__ bias,
    ushort_t* __restrict__ out, float* __restrict__ stats, int M)
{
  int tid = threadIdx.x;
  int wave = tid >> 6, lane = tid & 63;
  int m = lane & 15, quad = lane >> 4;
  int col0 = (blockIdx.y * 4 + wave) * 32;   // 8 col-groups of 32
  bf16x8 bfrag[2][8];
#pragma unroll
  for (int ct = 0; ct < 2; ++ct)
#pragma unroll
    for (int kt = 0; kt < 8; ++kt)
      bfrag[ct][kt] = *(const bf16x8*)(
          Wt + (size_t)(col0 + ct * 16 + m) * HID + kt * 32 + quad * 8);
  float bv[2] = {bias[col0 + m], bias[col0 + 16 + m]};
  float csum[2] = {0.f, 0.f}, csq[2] = {0.f, 0.f};
  int ntiles = M >> 4;  // M % 16 == 0
  for (int t = blockIdx.x; t < ntiles; t += gridDim.x) {
    const ushort_t* Ap = A + (size_t)(t * 16 + m) * HID + quad * 8;
    bf16x8 af[8];
#pragma unroll
    for (int kt = 0; kt < 8; ++kt) af[kt] = *(const bf16x8*)(Ap + kt * 32);
    f32x4 acc0 = (f32x4){0.f, 0.f, 0.f, 0.f};
    f32x4 acc1 = (f32x4){0.f, 0.f, 0.f, 0.f};
#pragma unroll
    for (int kt = 0; kt < 8; ++kt) {
      acc0 = __builtin_amdgcn_mfma_f32_16x16x32_bf16(af[kt], bfrag[0][kt], acc0, 0, 0, 0);
      acc1 = __builtin_amdgcn_mfma_f32_16x16x32_bf16(af[kt], bfrag[1][kt], acc1, 0, 0, 0);
    }
    int rb = t * 16 + quad * 4;
#pragma unroll
    for (int reg = 0; reg < 4; ++reg) {
      float o0 = acc0[reg] + bv[0];
      float o1 = acc1[reg] + bv[1];
      if (DO_RELU) { o0 = fmaxf(o0, 0.f); o1 = fmaxf(o1, 0.f); }
      out[(size_t)(rb + reg) * HID + col0 + m] = f2bf(o0);
      out[(size_t)(rb + reg) * HID + col0 + 16 + m] = f2bf(o1);
      if (STATS) {
        csum[0] += o0; csq[0] = fmaf(o0, o0, csq[0]);
        csum[1] += o1; csq[1] = fmaf(o1, o1, csq[1]);
      }
    }
  }
  if (STATS) {
#pragma unroll
    for (int ct = 0; ct < 2; ++ct) {
      float s = csum[ct], q = csq[ct];
      s += __shfl_xor(s, 16); s += __shfl_xor(s, 32);
      q += __shfl_xor(q, 16); q += __shfl_xor(q, 32);
      if (quad == 0) {
        unsafeAtomicAdd(&stats[col0 + ct * 16 + m], s);
        unsafeAtomicAdd(&stats[HID + col0 + ct * 16 + m], q);
      }
    }
  }
}

// also re-zeros stats for the next layer (single memset before the loop)
__global__ void k_bn_finalize(float* __restrict__ stats,
    const float* __restrict__ g, const float* __restrict__ b,
    float* __restrict__ ss, int n)
{
  int j = threadIdx.x;
  float inv_n = 1.f / (float)n;
  float mu = stats[j] * inv_n;
  float var = stats[HID + j] * inv_n - mu * mu;
  float rs = rsqrtf(var + 1e-5f);
  float sc = g[j] * rs;
  ss[j] = sc;
  ss[HID + j] = b[j] - mu * sc;
  stats[j] = 0.f;
  stats[HID + j] = 0.f;
}

// h(bf16) = relu(z*scale + shift) + h ; z bf16
__global__ __launch_bounds__(256) void k_bn_apply(const ushort_t* __restrict__ z,
    const float* __restrict__ ss, ushort_t* __restrict__ h, int total4)
{
  int idx = blockIdx.x * 256 + threadIdx.x;
  if (idx >= total4) return;
  int col = (idx & 63) * 4;
  ushort4 zv = *(const ushort4*)(z + (size_t)idx * 4);
  ushort4 hv = *(const ushort4*)(h + (size_t)idx * 4);
  float o0 = fmaxf(fmaf(bf2f(zv.x), ss[col + 0], ss[HID + col + 0]), 0.f) + bf2f(hv.x);
  float o1 = fmaxf(fmaf(bf2f(zv.y), ss[col + 1], ss[HID + col + 1]), 0.f) + bf2f(hv.y);
  float o2 = fmaxf(fmaf(bf2f(zv.z), ss[col + 2], ss[HID + col + 2]), 0.f) + bf2f(hv.z);
  float o3 = fmaxf(fmaf(bf2f(zv.w), ss[col + 3], ss[HID + col + 3]), 0.f) + bf2f(hv.w);
  *(ushort4*)(h + (size_t)idx * 4) = make_ushort4(f2bf(o0), f2bf(o1), f2bf(o2), f2bf(o3));
}

__device__ __forceinline__ int lbound(const int* __restrict__ b, int n, int key) {
  int lo = 0, hi = n;
  while (lo < hi) {
    int mid = (lo + hi) >> 1;
    if (b[mid] < key) lo = mid + 1; else hi = mid;
  }
  return lo;
}

// fused pool (batch sorted) + head MLP
__global__ __launch_bounds__(256) void k_head(const ushort_t* __restrict__ h,
    const int* __restrict__ batch,
    const float* __restrict__ W1, const float* __restrict__ b1,
    const float* __restrict__ W2, const float* __restrict__ b2,
    const float* __restrict__ W3, const float* __restrict__ b3,
    float* __restrict__ out)
{
  __shared__ float gf[3 * HID];
  __shared__ float g1[HID];
  __shared__ float red[4];
  int g = blockIdx.x, j = threadIdx.x;
  int lo = lbound(batch, N_NODES, g);
  int hi = lbound(batch, N_NODES, g + 1);
  float s = 0.f, mx = 0.f;  // h >= 0 by construction
  int i = lo;
  for (; i + 1 < hi; i += 2) {
    float v0 = bf2f(h[(size_t)i * HID + j]);
    float v1 = bf2f(h[(size_t)(i + 1) * HID + j]);
    s += v0 + v1; mx = fmaxf(mx, fmaxf(v0, v1));
  }
  if (i < hi) {
    float v = bf2f(h[(size_t)i * HID + j]);
    s += v; mx = fmaxf(mx, v);
  }
  float cntv = fmaxf((float)(hi - lo), 1.f);
  gf[j] = s / cntv;
  gf[HID + j] = s;
  gf[2 * HID + j] = mx;
  __syncthreads();
  float a0 = 0.f, a1 = 0.f, a2 = 0.f, a3 = 0.f;
  for (int k = 0; k < 3 * HID; k += 4) {
    a0 = fmaf(gf[k + 0], W1[(size_t)(k + 0) * HID + j], a0);
    a1 = fmaf(gf[k + 1], W1[(size_t)(k + 1) * HID + j], a1);
    a2 = fmaf(gf[k + 2], W1[(size_t)(k + 2) * HID + j], a2);
    a3 = fmaf(gf[k + 3], W1[(size_t)(k + 3) * HID + j], a3);
  }
  g1[j] = fmaxf(b1[j] + (a0 + a1) + (a2 + a3), 0.f);
  __syncthreads();
  float p = 0.f;
  if (j < 128) {
    float c0 = 0.f, c1 = 0.f, c2 = 0.f, c3 = 0.f;
    for (int k = 0; k < HID; k += 4) {
      c0 = fmaf(g1[k + 0], W2[(size_t)(k + 0) * 128 + j], c0);
      c1 = fmaf(g1[k + 1], W2[(size_t)(k + 1) * 128 + j], c1);
      c2 = fmaf(g1[k + 2], W2[(size_t)(k + 2) * 128 + j], c2);
      c3 = fmaf(g1[k + 3], W2[(size_t)(k + 3) * 128 + j], c3);
    }
    p = fmaxf(b2[j] + (c0 + c1) + (c2 + c3), 0.f) * W3[j];
  }
#pragma unroll
  for (int off = 32; off > 0; off >>= 1) p += __shfl_down(p, off);
  if ((j & 63) == 0) red[j >> 6] = p;
  __syncthreads();
  if (j == 0) out[g] = red[0] + red[1] + b3[0];
}

extern "C" void kernel_launch(void* const* d_in, const int* in_sizes, int n_in,
                              void* d_out, int out_size, void* d_ws, size_t ws_size,
                              hipStream_t stream)
{
  const float* x     = (const float*)d_in[0];
  const int*   ei    = (const int*)d_in[1];
  const float* ea    = (const float*)d_in[2];
  const int*   batch = (const int*)d_in[3];
  const float* encW  = (const float*)d_in[4];
  const float* encB  = (const float*)d_in[5];
  const float* edgeW = (const float*)d_in[6];
  const float* edgeB = (const float*)d_in[7];
  const float* W1    = (const float*)d_in[8];
  const float* b1    = (const float*)d_in[9];
  const float* W2    = (const float*)d_in[10];
  const float* b2    = (const float*)d_in[11];
  const float* bng   = (const float*)d_in[12];
  const float* bnb   = (const float*)d_in[13];
  const float* hW1   = (const float*)d_in[14];
  const float* hb1   = (const float*)d_in[15];
  const float* hW2   = (const float*)d_in[16];
  const float* hb2   = (const float*)d_in[17];
  const float* hW3   = (const float*)d_in[18];
  const float* hb3   = (const float*)d_in[19];
  float* out = (float*)d_out;

  const size_t NH = (size_t)N_NODES * HID;
  char* base = (char*)d_ws;
  auto alloc = [&](size_t bytes) -> char* {
    char* p = base; base += (bytes + 63) & ~(size_t)63; return p;
  };
  float*    stats = (float*)alloc(512 * 4);
  float*    ss    = (float*)alloc(512 * 4);
  int*      offs  = (int*)alloc(50001 * 4);
  int2*     epair = (int2*)alloc((size_t)N_EDGES * 8);
  ushort_t* Wt1   = (ushort_t*)alloc((size_t)NLAYERS * HID * HID * 2);
  ushort_t* Wt2   = (ushort_t*)alloc((size_t)NLAYERS * HID * HID * 2);
  ushort_t* zin   = (ushort_t*)alloc(NH * 2);  // also reused as z2
  ushort_t* z1    = (ushort_t*)alloc(NH * 2);
  ushort_t* h     = (ushort_t*)alloc(NH * 2);
  // total ~80.5 MB

  const int* src = ei;
  const int* dst = ei + N_EDGES;

  // CSR build + weight prep + stats zero (once per call)
  hipMemsetAsync(offs, 0, 50001 * sizeof(int), stream);
  hipMemsetAsync(stats, 0, 512 * sizeof(float), stream);
  k_hist<<<(N_EDGES + 255) / 256, 256, 0, stream>>>(dst, offs, N_EDGES);
  k_scan<<<1, 1024, 0, stream>>>(offs, N_NODES);
  k_fill<<<(N_EDGES + 255) / 256, 256, 0, stream>>>(src, dst, offs, epair, N_EDGES);
  k_prep<<<dim3(16, NLAYERS), 256, 0, stream>>>(W1, Wt1);
  k_prep<<<dim3(16, NLAYERS), 256, 0, stream>>>(W2, Wt2);

  k_encoder<<<(N_NODES + 7) / 8, 256, 0, stream>>>(x, encW, encB, h, N_NODES);

  const dim3 GGRID(391, 2);  // 782 blocks; wave w of block.y b owns cols (4b+w)*32
  for (int l = 0; l < NLAYERS; ++l) {
    k_gather<<<N_NODES / 4, 256, 0, stream>>>(
        h, ea, offs, epair, edgeW + (size_t)l * 5 * HID, edgeB + (size_t)l * HID,
        zin, N_NODES);
    // z1 = relu(zin @ W1 + b1)
    k_gemm_breg<1, 0><<<GGRID, 256, 0, stream>>>(
        zin, Wt1 + (size_t)l * HID * HID, b1 + (size_t)l * HID, z1, nullptr, N_NODES);
    // z2 = z1 @ W2 + b2 (into zin), fused column stats
    k_gemm_breg<0, 1><<<GGRID, 256, 0, stream>>>(
        z1, Wt2 + (size_t)l * HID * HID, b2 + (size_t)l * HID, zin, stats, N_NODES);
    k_bn_finalize<<<1, 256, 0, stream>>>(stats, bng + (size_t)l * HID,
                                         bnb + (size_t)l * HID, ss, N_NODES);
    k_bn_apply<<<(N_NODES * HID / 4 + 255) / 256, 256, 0, stream>>>(
        zin, ss, h, N_NODES * HID / 4);
  }

  k_head<<<G_GRAPHS, 256, 0, stream>>>(h, batch, hW1, hb1, hW2, hb2, hW3, hb3, out);
}

// Round 9
// 821.299 us; speedup vs baseline: 1.2491x; 1.0050x over previous
//
#include <hip/hip_runtime.h>

#define N_NODES 50000
#define N_EDGES 300000
#define G_GRAPHS 1024
#define HID 256
#define NLAYERS 4

typedef unsigned short ushort_t;
typedef __attribute__((ext_vector_type(8))) short bf16x8;
typedef __attribute__((ext_vector_type(8))) unsigned short u16x8;
typedef __attribute__((ext_vector_type(4))) float f32x4;

__device__ __forceinline__ float bf2f(ushort_t u) {
  unsigned int x = ((unsigned int)u) << 16;
  return __builtin_bit_cast(float, x);
}
__device__ __forceinline__ ushort_t f2bf(float f) {
  unsigned int x = __builtin_bit_cast(unsigned int, f);
  unsigned int lsb = (x >> 16) & 1u;
  x += 0x7fffu + lsb;
  return (ushort_t)(x >> 16);
}

// h(bf16) = relu(x @ encW + encB)
__global__ __launch_bounds__(256) void k_encoder(const float* __restrict__ x,
    const float* __restrict__ W, const float* __restrict__ b,
    ushort_t* __restrict__ h, int n)
{
  int j = threadIdx.x;
  float wcol[11];
#pragma unroll
  for (int k = 0; k < 11; ++k) wcol[k] = W[k * HID + j];
  float bj = b[j];
  __shared__ float xs[8][11];
  int base = blockIdx.x * 8;
  if (j < 88) {
    int r = j / 11, k = j % 11;
    int row = base + r;
    if (row < n) xs[r][k] = x[row * 11 + k];
  }
  __syncthreads();
#pragma unroll
  for (int r = 0; r < 8; ++r) {
    int row = base + r;
    if (row >= n) break;
    float acc = bj;
#pragma unroll
    for (int k = 0; k < 11; ++k) acc += xs[r][k] * wcol[k];
    h[(size_t)row * HID + j] = f2bf(fmaxf(acc, 0.f));
  }
}

// ---- CSR build ----
__global__ __launch_bounds__(256) void k_hist(const int* __restrict__ dst,
    int* __restrict__ offs, int E)
{
  int e = blockIdx.x * 256 + threadIdx.x;
  if (e < E) atomicAdd(&offs[dst[e]], 1);
}

__global__ __launch_bounds__(1024) void k_scan(int* __restrict__ offs, int n)
{
  __shared__ int wsum[16];
  __shared__ int s_carry;
  int tid = threadIdx.x, lane = tid & 63, wid = tid >> 6;
  if (tid == 0) s_carry = 0;
  __syncthreads();
  for (int base = 0; base < n; base += 1024) {
    int idx = base + tid;
    int v = (idx < n) ? offs[idx] : 0;
    int x = v;
#pragma unroll
    for (int off = 1; off < 64; off <<= 1) {
      int t = __shfl_up(x, off);
      if (lane >= off) x += t;
    }
    if (lane == 63) wsum[wid] = x;
    __syncthreads();
    if (wid == 0 && lane < 16) {
      int w = wsum[lane];
#pragma unroll
      for (int off = 1; off < 16; off <<= 1) {
        int t = __shfl_up(w, off);
        if (lane >= off) w += t;
      }
      wsum[lane] = w;
    }
    __syncthreads();
    int wbase = (wid == 0) ? 0 : wsum[wid - 1];
    int excl = s_carry + wbase + x - v;
    int total = wsum[15];
    __syncthreads();
    if (idx < n) offs[idx] = excl;
    if (tid == 0) s_carry += total;
    __syncthreads();
  }
  if (tid == 0) offs[n] = s_carry;
}

__global__ __launch_bounds__(256) void k_fill(const int* __restrict__ src,
    const int* __restrict__ dst, int* __restrict__ offs,
    int2* __restrict__ epair, int E)
{
  int e = blockIdx.x * 256 + threadIdx.x;
  if (e < E) {
    int d = dst[e];
    int p = atomicAdd(&offs[d], 1);
    epair[p] = make_int2(e, src[e]);
  }
}

// W [256][256] f32 -> Wt [n][k] bf16 (transposed), nmats via grid.y
__global__ __launch_bounds__(256) void k_prep(const float* __restrict__ W,
    ushort_t* __restrict__ Wt)
{
  __shared__ float ld[16][257];
  int mat = blockIdx.y;
  int k0 = blockIdx.x * 16;
  const float* Wm = W + (size_t)mat * HID * HID;
  ushort_t* Wtm = Wt + (size_t)mat * HID * HID;
  int tid = threadIdx.x;
#pragma unroll
  for (int i = 0; i < 16; ++i) ld[i][tid] = Wm[(size_t)(k0 + i) * HID + tid];
  __syncthreads();
#pragma unroll
  for (int v = 0; v < 4; ++v) {
    ushort4 u = make_ushort4(f2bf(ld[v*4+0][tid]), f2bf(ld[v*4+1][tid]),
                             f2bf(ld[v*4+2][tid]), f2bf(ld[v*4+3][tid]));
    *(ushort4*)&Wtm[(size_t)tid * HID + k0 + v * 4] = u;
  }
}

// generic W [K][N] f32 -> Wt [N][K] bf16
__global__ __launch_bounds__(256) void k_prept(const float* __restrict__ W,
    ushort_t* __restrict__ Wt, int K, int N)
{
  int idx = blockIdx.x * 256 + threadIdx.x;
  if (idx >= K * N) return;
  int n = idx / K, k = idx % K;
  Wt[idx] = f2bf(W[(size_t)k * N + n]);
}

// one wave per node, pairwise-pipelined over in-edges:
// zin[i] = h[i] + sum relu(h[src] + ea@eW + eb). Block 0 zeroes stats.
__global__ __launch_bounds__(256) void k_gather(const ushort_t* __restrict__ h,
    const float* __restrict__ ea, const int* __restrict__ offs,
    const int2* __restrict__ epair, const float* __restrict__ eW,
    const float* __restrict__ eb, ushort_t* __restrict__ zin,
    float* __restrict__ stats, int n)
{
  int tid = threadIdx.x;
  if (blockIdx.x == 0) { stats[tid] = 0.f; stats[HID + tid] = 0.f; }
  int wave = tid >> 6, lane = tid & 63;
  int node = blockIdx.x * 4 + wave;
  int c4 = lane * 4;
  float4 w0 = *(const float4*)&eW[0 * HID + c4];
  float4 w1 = *(const float4*)&eW[1 * HID + c4];
  float4 w2 = *(const float4*)&eW[2 * HID + c4];
  float4 w3 = *(const float4*)&eW[3 * HID + c4];
  float4 w4 = *(const float4*)&eW[4 * HID + c4];
  float4 bi = *(const float4*)&eb[c4];
  if (node >= n) return;
  int lo = (node == 0) ? 0 : offs[node - 1];
  int hi = offs[node];
  ushort4 ho = *(const ushort4*)&h[(size_t)node * HID + c4];
  float ax = bf2f(ho.x), ay = bf2f(ho.y), az = bf2f(ho.z), aw = bf2f(ho.w);
  int p = lo;
  for (; p + 1 < hi; p += 2) {
    int2 pa = epair[p], pb = epair[p + 1];
    const float* eA = ea + (size_t)pa.x * 5;
    const float* eB = ea + (size_t)pb.x * 5;
    float a0 = eA[0], a1 = eA[1], a2 = eA[2], a3 = eA[3], a4 = eA[4];
    float b0 = eB[0], b1 = eB[1], b2 = eB[2], b3 = eB[3], b4 = eB[4];
    ushort4 hA = *(const ushort4*)&h[(size_t)pa.y * HID + c4];
    ushort4 hB = *(const ushort4*)&h[(size_t)pb.y * HID + c4];
    float m0 = bi.x, m1 = bi.y, m2 = bi.z, m3 = bi.w;
    m0 = fmaf(a0, w0.x, m0); m1 = fmaf(a0, w0.y, m1); m2 = fmaf(a0, w0.z, m2); m3 = fmaf(a0, w0.w, m3);
    m0 = fmaf(a1, w1.x, m0); m1 = fmaf(a1, w1.y, m1); m2 = fmaf(a1, w1.z, m2); m3 = fmaf(a1, w1.w, m3);
    m0 = fmaf(a2, w2.x, m0); m1 = fmaf(a2, w2.y, m1); m2 = fmaf(a2, w2.z, m2); m3 = fmaf(a2, w2.w, m3);
    m0 = fmaf(a3, w3.x, m0); m1 = fmaf(a3, w3.y, m1); m2 = fmaf(a3, w3.z, m2); m3 = fmaf(a3, w3.w, m3);
    m0 = fmaf(a4, w4.x, m0); m1 = fmaf(a4, w4.y, m1); m2 = fmaf(a4, w4.z, m2); m3 = fmaf(a4, w4.w, m3);
    m0 += bf2f(hA.x); m1 += bf2f(hA.y); m2 += bf2f(hA.z); m3 += bf2f(hA.w);
    ax += fmaxf(m0, 0.f); ay += fmaxf(m1, 0.f); az += fmaxf(m2, 0.f); aw += fmaxf(m3, 0.f);
    float n0 = bi.x, n1 = bi.y, n2 = bi.z, n3 = bi.w;
    n0 = fmaf(b0, w0.x, n0); n1 = fmaf(b0, w0.y, n1); n2 = fmaf(b0, w0.z, n2); n3 = fmaf(b0, w0.w, n3);
    n0 = fmaf(b1, w1.x, n0); n1 = fmaf(b1, w1.y, n1); n2 = fmaf(b1, w1.z, n2); n3 = fmaf(b1, w1.w, n3);
    n0 = fmaf(b2, w2.x, n0); n1 = fmaf(b2, w2.y, n1); n2 = fmaf(b2, w2.z, n2); n3 = fmaf(b2, w2.w, n3);
    n0 = fmaf(b3, w3.x, n0); n1 = fmaf(b3, w3.y, n1); n2 = fmaf(b3, w3.z, n2); n3 = fmaf(b3, w3.w, n3);
    n0 = fmaf(b4, w4.x, n0); n1 = fmaf(b4, w4.y, n1); n2 = fmaf(b4, w4.z, n2); n3 = fmaf(b4, w4.w, n3);
    n0 += bf2f(hB.x); n1 += bf2f(hB.y); n2 += bf2f(hB.z); n3 += bf2f(hB.w);
    ax += fmaxf(n0, 0.f); ay += fmaxf(n1, 0.f); az += fmaxf(n2, 0.f); aw += fmaxf(n3, 0.f);
  }
  if (p < hi) {
    int2 pa = epair[p];
    const float* eA = ea + (size_t)pa.x * 5;
    float a0 = eA[0], a1 = eA[1], a2 = eA[2], a3 = eA[3], a4 = eA[4];
    ushort4 hA = *(const ushort4*)&h[(size_t)pa.y * HID + c4];
    float m0 = bi.x, m1 = bi.y, m2 = bi.z, m3 = bi.w;
    m0 = fmaf(a0, w0.x, m0); m1 = fmaf(a0, w0.y, m1); m2 = fmaf(a0, w0.z, m2); m3 = fmaf(a0, w0.w, m3);
    m0 = fmaf(a1, w1.x, m0); m1 = fmaf(a1, w1.y, m1); m2 = fmaf(a1, w1.z, m2); m3 = fmaf(a1, w1.w, m3);
    m0 = fmaf(a2, w2.x, m0); m1 = fmaf(a2, w2.y, m1); m2 = fmaf(a2, w2.z, m2); m3 = fmaf(a2, w2.w, m3);
    m0 = fmaf(a3, w3.x, m0); m1 = fmaf(a3, w3.y, m1); m2 = fmaf(a3, w3.z, m2); m3 = fmaf(a3, w3.w, m3);
    m0 = fmaf(a4, w4.x, m0); m1 = fmaf(a4, w4.y, m1); m2 = fmaf(a4, w4.z, m2); m3 = fmaf(a4, w4.w, m3);
    m0 += bf2f(hA.x); m1 += bf2f(hA.y); m2 += bf2f(hA.z); m3 += bf2f(hA.w);
    ax += fmaxf(m0, 0.f); ay += fmaxf(m1, 0.f); az += fmaxf(m2, 0.f); aw += fmaxf(m3, 0.f);
  }
  *(ushort4*)&zin[(size_t)node * HID + c4] =
      make_ushort4(f2bf(ax), f2bf(ay), f2bf(az), f2bf(aw));
}

// B-in-registers MFMA GEMM (main layers): out = A @ Wt^T + bias
template<int DO_RELU, int STATS>
__global__ __launch_bounds__(256, 3) void k_gemm_breg(const ushort_t* __restrict__ A,
    const ushort_t* __restrict__ Wt, const float* __restrict__ bias,
    ushort_t* __restrict__ out, float* __restrict__ stats, int M)
{
  int tid = threadIdx.x;
  int wave = tid >> 6, lane = tid & 63;
  int m = lane & 15, quad = lane >> 4;
  int col0 = (blockIdx.y * 4 + wave) * 32;   // 8 col-groups of 32
  bf16x8 bfrag[2][8];
#pragma unroll
  for (int ct = 0; ct < 2; ++ct)
#pragma unroll
    for (int kt = 0; kt < 8; ++kt)
      bfrag[ct][kt] = *(const bf16x8*)(
          Wt + (size_t)(col0 + ct * 16 + m) * HID + kt * 32 + quad * 8);
  float bv[2] = {bias[col0 + m], bias[col0 + 16 + m]};
  float csum[2] = {0.f, 0.f}, csq[2] = {0.f, 0.f};
  int ntiles = M >> 4;
  for (int t = blockIdx.x; t < ntiles; t += gridDim.x) {
    const ushort_t* Ap = A + (size_t)(t * 16 + m) * HID + quad * 8;
    bf16x8 af[8];
#pragma unroll
    for (int kt = 0; kt < 8; ++kt) af[kt] = *(const bf16x8*)(Ap + kt * 32);
    f32x4 acc0 = (f32x4){0.f, 0.f, 0.f, 0.f};
    f32x4 acc1 = (f32x4){0.f, 0.f, 0.f, 0.f};
#pragma unroll
    for (int kt = 0; kt < 8; ++kt) {
      acc0 = __builtin_amdgcn_mfma_f32_16x16x32_bf16(af[kt], bfrag[0][kt], acc0, 0, 0, 0);
      acc1 = __builtin_amdgcn_mfma_f32_16x16x32_bf16(af[kt], bfrag[1][kt], acc1, 0, 0, 0);
    }
    int rb = t * 16 + quad * 4;
#pragma unroll
    for (int reg = 0; reg < 4; ++reg) {
      float o0 = acc0[reg] + bv[0];
      float o1 = acc1[reg] + bv[1];
      if (DO_RELU) { o0 = fmaxf(o0, 0.f); o1 = fmaxf(o1, 0.f); }
      out[(size_t)(rb + reg) * HID + col0 + m] = f2bf(o0);
      out[(size_t)(rb + reg) * HID + col0 + 16 + m] = f2bf(o1);
      if (STATS) {
        csum[0] += o0; csq[0] = fmaf(o0, o0, csq[0]);
        csum[1] += o1; csq[1] = fmaf(o1, o1, csq[1]);
      }
    }
  }
  if (STATS) {
#pragma unroll
    for (int ct = 0; ct < 2; ++ct) {
      float s = csum[ct], q = csq[ct];
      s += __shfl_xor(s, 16); s += __shfl_xor(s, 32);
      q += __shfl_xor(q, 16); q += __shfl_xor(q, 32);
      if (quad == 0) {
        unsafeAtomicAdd(&stats[col0 + ct * 16 + m], s);
        unsafeAtomicAdd(&stats[HID + col0 + ct * 16 + m], q);
      }
    }
  }
}

// h(bf16) = relu(z*scale + shift) + h ; scale/shift computed from raw stats
__global__ __launch_bounds__(256) void k_bn_apply(const ushort_t* __restrict__ z,
    const float* __restrict__ stats, const float* __restrict__ g,
    const float* __restrict__ b, ushort_t* __restrict__ h, int total4)
{
  int idx = blockIdx.x * 256 + threadIdx.x;
  if (idx >= total4) return;
  int col = (idx & 63) * 4;
  const float inv_n = 1.f / (float)N_NODES;
  float sc[4], sh[4];
#pragma unroll
  for (int c = 0; c < 4; ++c) {
    float mu = stats[col + c] * inv_n;
    float var = stats[HID + col + c] * inv_n - mu * mu;
    float rs = rsqrtf(var + 1e-5f);
    sc[c] = g[col + c] * rs;
    sh[c] = b[col + c] - mu * sc[c];
  }
  ushort4 zv = *(const ushort4*)(z + (size_t)idx * 4);
  ushort4 hv = *(const ushort4*)(h + (size_t)idx * 4);
  float o0 = fmaxf(fmaf(bf2f(zv.x), sc[0], sh[0]), 0.f) + bf2f(hv.x);
  float o1 = fmaxf(fmaf(bf2f(zv.y), sc[1], sh[1]), 0.f) + bf2f(hv.y);
  float o2 = fmaxf(fmaf(bf2f(zv.z), sc[2], sh[2]), 0.f) + bf2f(hv.z);
  float o3 = fmaxf(fmaf(bf2f(zv.w), sc[3], sh[3]), 0.f) + bf2f(hv.w);
  *(ushort4*)(h + (size_t)idx * 4) = make_ushort4(f2bf(o0), f2bf(o1), f2bf(o2), f2bf(o3));
}

__device__ __forceinline__ int lbound(const int* __restrict__ b, int n, int key) {
  int lo = 0, hi = n;
  while (lo < hi) {
    int mid = (lo + hi) >> 1;
    if (b[mid] < key) lo = mid + 1; else hi = mid;
  }
  return lo;
}

// pool per graph (batch sorted): gf[g] = [mean | sum | max] as bf16
__global__ __launch_bounds__(256) void k_pool(const ushort_t* __restrict__ h,
    const int* __restrict__ batch, ushort_t* __restrict__ gf)
{
  int g = blockIdx.x, j = threadIdx.x;
  int lo = lbound(batch, N_NODES, g);
  int hi = lbound(batch, N_NODES, g + 1);
  float s = 0.f, mx = 0.f;  // h >= 0 by construction
  int i = lo;
  for (; i + 1 < hi; i += 2) {
    float v0 = bf2f(h[(size_t)i * HID + j]);
    float v1 = bf2f(h[(size_t)(i + 1) * HID + j]);
    s += v0 + v1; mx = fmaxf(mx, fmaxf(v0, v1));
  }
  if (i < hi) {
    float v = bf2f(h[(size_t)i * HID + j]);
    s += v; mx = fmaxf(mx, v);
  }
  float cntv = fmaxf((float)(hi - lo), 1.f);
  size_t base = (size_t)g * 768;
  gf[base + j] = f2bf(s / cntv);
  gf[base + 256 + j] = f2bf(s);
  gf[base + 512 + j] = f2bf(mx);
}

// small B-in-registers MFMA GEMM for the head: out[M,N] = A[M,K] @ Bt^T + bias
// K = KT*32, wave owns 16 cols (group = blockIdx.y*4+wave)
template<int KT, int DO_RELU>
__global__ __launch_bounds__(256, 1) void k_head_gemm(const ushort_t* __restrict__ A,
    const ushort_t* __restrict__ Bt, const float* __restrict__ bias,
    ushort_t* __restrict__ out, int M, int N)
{
  const int K = KT * 32;
  int tid = threadIdx.x;
  int wave = tid >> 6, lane = tid & 63;
  int m = lane & 15, quad = lane >> 4;
  int col = (blockIdx.y * 4 + wave) * 16 + m;
  bf16x8 bfrag[KT];
#pragma unroll
  for (int kt = 0; kt < KT; ++kt)
    bfrag[kt] = *(const bf16x8*)(Bt + (size_t)col * K + kt * 32 + quad * 8);
  float bv = bias[col];
  int ntiles = M >> 4;
  for (int t = blockIdx.x; t < ntiles; t += gridDim.x) {
    const ushort_t* Ap = A + (size_t)(t * 16 + m) * K + quad * 8;
    bf16x8 af[KT];
#pragma unroll
    for (int kt = 0; kt < KT; ++kt) af[kt] = *(const bf16x8*)(Ap + kt * 32);
    f32x4 acc = (f32x4){0.f, 0.f, 0.f, 0.f};
#pragma unroll
    for (int kt = 0; kt < KT; ++kt)
      acc = __builtin_amdgcn_mfma_f32_16x16x32_bf16(af[kt], bfrag[kt], acc, 0, 0, 0);
    int rb = t * 16 + quad * 4;
#pragma unroll
    for (int reg = 0; reg < 4; ++reg) {
      float o = acc[reg] + bv;
      if (DO_RELU) o = fmaxf(o, 0.f);
      out[(size_t)(rb + reg) * N + col] = f2bf(o);
    }
  }
}

// out[g] = dot(g2[g], W3) + b3; one wave per graph
__global__ __launch_bounds__(256) void k_head_out(const ushort_t* __restrict__ g2,
    const float* __restrict__ W3, const float* __restrict__ b3,
    float* __restrict__ out)
{
  int wave = threadIdx.x >> 6, lane = threadIdx.x & 63;
  int g = blockIdx.x * 4 + wave;
  ushort2 v = *(const ushort2*)&g2[(size_t)g * 128 + lane * 2];
  float p = bf2f(v.x) * W3[lane * 2] + bf2f(v.y) * W3[lane * 2 + 1];
#pragma unroll
  for (int off = 32; off > 0; off >>= 1) p += __shfl_down(p, off);
  if (lane == 0) out[g] = p + b3[0];
}

extern "C" void kernel_launch(void* const* d_in, const int* in_sizes, int n_in,
                              void* d_out, int out_size, void* d_ws, size_t ws_size,
                              hipStream_t stream)
{
  const float* x     = (const float*)d_in[0];
  const int*   ei    = (const int*)d_in[1];
  const float* ea    = (const float*)d_in[2];
  const int*   batch = (const int*)d_in[3];
  const float* encW  = (const float*)d_in[4];
  const float* encB  = (const float*)d_in[5];
  const float* edgeW = (const float*)d_in[6];
  const float* edgeB = (const float*)d_in[7];
  const float* W1    = (const float*)d_in[8];
  const float* b1    = (const float*)d_in[9];
  const float* W2    = (const float*)d_in[10];
  const float* b2    = (const float*)d_in[11];
  const float* bng   = (const float*)d_in[12];
  const float* bnb   = (const float*)d_in[13];
  const float* hW1   = (const float*)d_in[14];
  const float* hb1   = (const float*)d_in[15];
  const float* hW2   = (const float*)d_in[16];
  const float* hb2   = (const float*)d_in[17];
  const float* hW3   = (const float*)d_in[18];
  const float* hb3   = (const float*)d_in[19];
  float* out = (float*)d_out;

  const size_t NH = (size_t)N_NODES * HID;
  char* base = (char*)d_ws;
  auto alloc = [&](size_t bytes) -> char* {
    char* p = base; base += (bytes + 63) & ~(size_t)63; return p;
  };
  float*    stats = (float*)alloc(512 * 4);
  int*      offs  = (int*)alloc(50001 * 4);
  int2*     epair = (int2*)alloc((size_t)N_EDGES * 8);
  ushort_t* Wt1   = (ushort_t*)alloc((size_t)NLAYERS * HID * HID * 2);
  ushort_t* Wt2   = (ushort_t*)alloc((size_t)NLAYERS * HID * HID * 2);
  ushort_t* hW1t  = (ushort_t*)alloc((size_t)768 * 256 * 2);
  ushort_t* hW2t  = (ushort_t*)alloc((size_t)256 * 128 * 2);
  ushort_t* gf    = (ushort_t*)alloc((size_t)G_GRAPHS * 768 * 2);
  ushort_t* g1    = (ushort_t*)alloc((size_t)G_GRAPHS * 256 * 2);
  ushort_t* g2    = (ushort_t*)alloc((size_t)G_GRAPHS * 128 * 2);
  ushort_t* zin   = (ushort_t*)alloc(NH * 2);  // also reused as z2
  ushort_t* z1    = (ushort_t*)alloc(NH * 2);
  ushort_t* h     = (ushort_t*)alloc(NH * 2);
  // total ~84 MB

  const int* src = ei;
  const int* dst = ei + N_EDGES;

  // setup: CSR build + weight prep (once per call)
  hipMemsetAsync(offs, 0, 50001 * sizeof(int), stream);
  k_hist<<<(N_EDGES + 255) / 256, 256, 0, stream>>>(dst, offs, N_EDGES);
  k_scan<<<1, 1024, 0, stream>>>(offs, N_NODES);
  k_fill<<<(N_EDGES + 255) / 256, 256, 0, stream>>>(src, dst, offs, epair, N_EDGES);
  k_prep<<<dim3(16, NLAYERS), 256, 0, stream>>>(W1, Wt1);
  k_prep<<<dim3(16, NLAYERS), 256, 0, stream>>>(W2, Wt2);
  k_prept<<<(768 * 256 + 255) / 256, 256, 0, stream>>>(hW1, hW1t, 768, 256);
  k_prept<<<(256 * 128 + 255) / 256, 256, 0, stream>>>(hW2, hW2t, 256, 128);

  k_encoder<<<(N_NODES + 7) / 8, 256, 0, stream>>>(x, encW, encB, h, N_NODES);

  const dim3 GGRID(391, 2);
  for (int l = 0; l < NLAYERS; ++l) {
    k_gather<<<N_NODES / 4, 256, 0, stream>>>(
        h, ea, offs, epair, edgeW + (size_t)l * 5 * HID, edgeB + (size_t)l * HID,
        zin, stats, N_NODES);
    k_gemm_breg<1, 0><<<GGRID, 256, 0, stream>>>(
        zin, Wt1 + (size_t)l * HID * HID, b1 + (size_t)l * HID, z1, nullptr, N_NODES);
    k_gemm_breg<0, 1><<<GGRID, 256, 0, stream>>>(
        z1, Wt2 + (size_t)l * HID * HID, b2 + (size_t)l * HID, zin, stats, N_NODES);
    k_bn_apply<<<(N_NODES * HID / 4 + 255) / 256, 256, 0, stream>>>(
        zin, stats, bng + (size_t)l * HID, bnb + (size_t)l * HID, h, N_NODES * HID / 4);
  }

  k_pool<<<G_GRAPHS, 256, 0, stream>>>(h, batch, gf);
  k_head_gemm<24, 1><<<dim3(16, 4), 256, 0, stream>>>(gf, hW1t, hb1, g1, G_GRAPHS, 256);
  k_head_gemm<8, 1><<<dim3(16, 2), 256, 0, stream>>>(g1, hW2t, hb2, g2, G_GRAPHS, 128);
  k_head_out<<<G_GRAPHS / 4, 256, 0, stream>>>(g2, hW3, hb3, out);
}

// Round 10
// 705.894 us; speedup vs baseline: 1.4533x; 1.1635x over previous
//
#include <hip/hip_runtime.h>

#define N_NODES 50000
#define N_EDGES 300000
#define G_GRAPHS 1024
#define HID 256
#define NLAYERS 4

typedef unsigned short ushort_t;
typedef __attribute__((ext_vector_type(8))) short bf16x8;
typedef __attribute__((ext_vector_type(8))) unsigned short u16x8;
typedef __attribute__((ext_vector_type(4))) float f32x4;

__device__ __forceinline__ float bf2f(ushort_t u) {
  unsigned int x = ((unsigned int)u) << 16;
  return __builtin_bit_cast(float, x);
}
__device__ __forceinline__ ushort_t f2bf(float f) {
  unsigned int x = __builtin_bit_cast(unsigned int, f);
  unsigned int lsb = (x >> 16) & 1u;
  x += 0x7fffu + lsb;
  return (ushort_t)(x >> 16);
}

// h(bf16) = relu(x @ encW + encB)
__global__ __launch_bounds__(256) void k_encoder(const float* __restrict__ x,
    const float* __restrict__ W, const float* __restrict__ b,
    ushort_t* __restrict__ h, int n)
{
  int j = threadIdx.x;
  float wcol[11];
#pragma unroll
  for (int k = 0; k < 11; ++k) wcol[k] = W[k * HID + j];
  float bj = b[j];
  __shared__ float xs[8][11];
  int base = blockIdx.x * 8;
  if (j < 88) {
    int r = j / 11, k = j % 11;
    int row = base + r;
    if (row < n) xs[r][k] = x[row * 11 + k];
  }
  __syncthreads();
#pragma unroll
  for (int r = 0; r < 8; ++r) {
    int row = base + r;
    if (row >= n) break;
    float acc = bj;
#pragma unroll
    for (int k = 0; k < 11; ++k) acc += xs[r][k] * wcol[k];
    h[(size_t)row * HID + j] = f2bf(fmaxf(acc, 0.f));
  }
}

// ---- CSR build ----
__global__ __launch_bounds__(256) void k_hist(const int* __restrict__ dst,
    int* __restrict__ offs, int E)
{
  int e = blockIdx.x * 256 + threadIdx.x;
  if (e < E) atomicAdd(&offs[dst[e]], 1);
}

__global__ __launch_bounds__(1024) void k_scan(int* __restrict__ offs, int n)
{
  __shared__ int wsum[16];
  __shared__ int s_carry;
  int tid = threadIdx.x, lane = tid & 63, wid = tid >> 6;
  if (tid == 0) s_carry = 0;
  __syncthreads();
  for (int base = 0; base < n; base += 1024) {
    int idx = base + tid;
    int v = (idx < n) ? offs[idx] : 0;
    int x = v;
#pragma unroll
    for (int off = 1; off < 64; off <<= 1) {
      int t = __shfl_up(x, off);
      if (lane >= off) x += t;
    }
    if (lane == 63) wsum[wid] = x;
    __syncthreads();
    if (wid == 0 && lane < 16) {
      int w = wsum[lane];
#pragma unroll
      for (int off = 1; off < 16; off <<= 1) {
        int t = __shfl_up(w, off);
        if (lane >= off) w += t;
      }
      wsum[lane] = w;
    }
    __syncthreads();
    int wbase = (wid == 0) ? 0 : wsum[wid - 1];
    int excl = s_carry + wbase + x - v;
    int total = wsum[15];
    __syncthreads();
    if (idx < n) offs[idx] = excl;
    if (tid == 0) s_carry += total;
    __syncthreads();
  }
  if (tid == 0) offs[n] = s_carry;
}

__global__ __launch_bounds__(256) void k_fill(const int* __restrict__ src,
    const int* __restrict__ dst, int* __restrict__ offs,
    int2* __restrict__ epair, int E)
{
  int e = blockIdx.x * 256 + threadIdx.x;
  if (e < E) {
    int d = dst[e];
    int p = atomicAdd(&offs[d], 1);
    epair[p] = make_int2(e, src[e]);
  }
}

// W [256][256] f32 -> Wt [n][k] bf16 (transposed), nmats via grid.y
__global__ __launch_bounds__(256) void k_prep(const float* __restrict__ W,
    ushort_t* __restrict__ Wt)
{
  __shared__ float ld[16][257];
  int mat = blockIdx.y;
  int k0 = blockIdx.x * 16;
  const float* Wm = W + (size_t)mat * HID * HID;
  ushort_t* Wtm = Wt + (size_t)mat * HID * HID;
  int tid = threadIdx.x;
#pragma unroll
  for (int i = 0; i < 16; ++i) ld[i][tid] = Wm[(size_t)(k0 + i) * HID + tid];
  __syncthreads();
#pragma unroll
  for (int v = 0; v < 4; ++v) {
    ushort4 u = make_ushort4(f2bf(ld[v*4+0][tid]), f2bf(ld[v*4+1][tid]),
                             f2bf(ld[v*4+2][tid]), f2bf(ld[v*4+3][tid]));
    *(ushort4*)&Wtm[(size_t)tid * HID + k0 + v * 4] = u;
  }
}

// generic W [K][N] f32 -> Wt [N][K] bf16
__global__ __launch_bounds__(256) void k_prept(const float* __restrict__ W,
    ushort_t* __restrict__ Wt, int K, int N)
{
  int idx = blockIdx.x * 256 + threadIdx.x;
  if (idx >= K * N) return;
  int n = idx / K, k = idx % K;
  Wt[idx] = f2bf(W[(size_t)k * N + n]);
}

// one wave per node, pairwise-pipelined over in-edges:
// zin[i] = h[i] + sum relu(h[src] + ea@eW + eb). Block 0 zeroes stats.
__global__ __launch_bounds__(256) void k_gather(const ushort_t* __restrict__ h,
    const float* __restrict__ ea, const int* __restrict__ offs,
    const int2* __restrict__ epair, const float* __restrict__ eW,
    const float* __restrict__ eb, ushort_t* __restrict__ zin,
    float* __restrict__ stats, int n)
{
  int tid = threadIdx.x;
  if (blockIdx.x == 0) { stats[tid] = 0.f; stats[HID + tid] = 0.f; }
  int wave = tid >> 6, lane = tid & 63;
  int node = blockIdx.x * 4 + wave;
  int c4 = lane * 4;
  float4 w0 = *(const float4*)&eW[0 * HID + c4];
  float4 w1 = *(const float4*)&eW[1 * HID + c4];
  float4 w2 = *(const float4*)&eW[2 * HID + c4];
  float4 w3 = *(const float4*)&eW[3 * HID + c4];
  float4 w4 = *(const float4*)&eW[4 * HID + c4];
  float4 bi = *(const float4*)&eb[c4];
  if (node >= n) return;
  int lo = (node == 0) ? 0 : offs[node - 1];
  int hi = offs[node];
  ushort4 ho = *(const ushort4*)&h[(size_t)node * HID + c4];
  float ax = bf2f(ho.x), ay = bf2f(ho.y), az = bf2f(ho.z), aw = bf2f(ho.w);
  int p = lo;
  for (; p + 1 < hi; p += 2) {
    int2 pa = epair[p], pb = epair[p + 1];
    const float* eA = ea + (size_t)pa.x * 5;
    const float* eB = ea + (size_t)pb.x * 5;
    float a0 = eA[0], a1 = eA[1], a2 = eA[2], a3 = eA[3], a4 = eA[4];
    float b0 = eB[0], b1 = eB[1], b2 = eB[2], b3 = eB[3], b4 = eB[4];
    ushort4 hA = *(const ushort4*)&h[(size_t)pa.y * HID + c4];
    ushort4 hB = *(const ushort4*)&h[(size_t)pb.y * HID + c4];
    float m0 = bi.x, m1 = bi.y, m2 = bi.z, m3 = bi.w;
    m0 = fmaf(a0, w0.x, m0); m1 = fmaf(a0, w0.y, m1); m2 = fmaf(a0, w0.z, m2); m3 = fmaf(a0, w0.w, m3);
    m0 = fmaf(a1, w1.x, m0); m1 = fmaf(a1, w1.y, m1); m2 = fmaf(a1, w1.z, m2); m3 = fmaf(a1, w1.w, m3);
    m0 = fmaf(a2, w2.x, m0); m1 = fmaf(a2, w2.y, m1); m2 = fmaf(a2, w2.z, m2); m3 = fmaf(a2, w2.w, m3);
    m0 = fmaf(a3, w3.x, m0); m1 = fmaf(a3, w3.y, m1); m2 = fmaf(a3, w3.z, m2); m3 = fmaf(a3, w3.w, m3);
    m0 = fmaf(a4, w4.x, m0); m1 = fmaf(a4, w4.y, m1); m2 = fmaf(a4, w4.z, m2); m3 = fmaf(a4, w4.w, m3);
    m0 += bf2f(hA.x); m1 += bf2f(hA.y); m2 += bf2f(hA.z); m3 += bf2f(hA.w);
    ax += fmaxf(m0, 0.f); ay += fmaxf(m1, 0.f); az += fmaxf(m2, 0.f); aw += fmaxf(m3, 0.f);
    float n0 = bi.x, n1 = bi.y, n2 = bi.z, n3 = bi.w;
    n0 = fmaf(b0, w0.x, n0); n1 = fmaf(b0, w0.y, n1); n2 = fmaf(b0, w0.z, n2); n3 = fmaf(b0, w0.w, n3);
    n0 = fmaf(b1, w1.x, n0); n1 = fmaf(b1, w1.y, n1); n2 = fmaf(b1, w1.z, n2); n3 = fmaf(b1, w1.w, n3);
    n0 = fmaf(b2, w2.x, n0); n1 = fmaf(b2, w2.y, n1); n2 = fmaf(b2, w2.z, n2); n3 = fmaf(b2, w2.w, n3);
    n0 = fmaf(b3, w3.x, n0); n1 = fmaf(b3, w3.y, n1); n2 = fmaf(b3, w3.z, n2); n3 = fmaf(b3, w3.w, n3);
    n0 = fmaf(b4, w4.x, n0); n1 = fmaf(b4, w4.y, n1); n2 = fmaf(b4, w4.z, n2); n3 = fmaf(b4, w4.w, n3);
    n0 += bf2f(hB.x); n1 += bf2f(hB.y); n2 += bf2f(hB.z); n3 += bf2f(hB.w);
    ax += fmaxf(n0, 0.f); ay += fmaxf(n1, 0.f); az += fmaxf(n2, 0.f); aw += fmaxf(n3, 0.f);
  }
  if (p < hi) {
    int2 pa = epair[p];
    const float* eA = ea + (size_t)pa.x * 5;
    float a0 = eA[0], a1 = eA[1], a2 = eA[2], a3 = eA[3], a4 = eA[4];
    ushort4 hA = *(const ushort4*)&h[(size_t)pa.y * HID + c4];
    float m0 = bi.x, m1 = bi.y, m2 = bi.z, m3 = bi.w;
    m0 = fmaf(a0, w0.x, m0); m1 = fmaf(a0, w0.y, m1); m2 = fmaf(a0, w0.z, m2); m3 = fmaf(a0, w0.w, m3);
    m0 = fmaf(a1, w1.x, m0); m1 = fmaf(a1, w1.y, m1); m2 = fmaf(a1, w1.z, m2); m3 = fmaf(a1, w1.w, m3);
    m0 = fmaf(a2, w2.x, m0); m1 = fmaf(a2, w2.y, m1); m2 = fmaf(a2, w2.z, m2); m3 = fmaf(a2, w2.w, m3);
    m0 = fmaf(a3, w3.x, m0); m1 = fmaf(a3, w3.y, m1); m2 = fmaf(a3, w3.z, m2); m3 = fmaf(a3, w3.w, m3);
    m0 = fmaf(a4, w4.x, m0); m1 = fmaf(a4, w4.y, m1); m2 = fmaf(a4, w4.z, m2); m3 = fmaf(a4, w4.w, m3);
    m0 += bf2f(hA.x); m1 += bf2f(hA.y); m2 += bf2f(hA.z); m3 += bf2f(hA.w);
    ax += fmaxf(m0, 0.f); ay += fmaxf(m1, 0.f); az += fmaxf(m2, 0.f); aw += fmaxf(m3, 0.f);
  }
  *(ushort4*)&zin[(size_t)node * HID + c4] =
      make_ushort4(f2bf(ax), f2bf(ay), f2bf(az), f2bf(aw));
}

// B-in-registers MFMA GEMM, 64 cols/wave: out = A @ Wt^T + bias.
// One 4-wave block covers all 256 cols of a row-tile -> A-frag loads of the
// 4 waves hit the same CU's L1 (A fabric traffic ~1x instead of 8x).
// Software-pipelined A prefetch across the grid-stride row-tile loop.
template<int DO_RELU, int STATS>
__global__ __launch_bounds__(256, 2) void k_gemm_breg(const ushort_t* __restrict__ A,
    const ushort_t* __restrict__ Wt, const float* __restrict__ bias,
    ushort_t* __restrict__ out, float* __restrict__ stats, int M)
{
  int tid = threadIdx.x;
  int wave = tid >> 6, lane = tid & 63;
  int m = lane & 15, quad = lane >> 4;
  int col0 = wave * 64;   // 4 col-groups of 16
  bf16x8 bfrag[4][8];
#pragma unroll
  for (int ct = 0; ct < 4; ++ct)
#pragma unroll
    for (int kt = 0; kt < 8; ++kt)
      bfrag[ct][kt] = *(const bf16x8*)(
          Wt + (size_t)(col0 + ct * 16 + m) * HID + kt * 32 + quad * 8);
  float bv[4];
#pragma unroll
  for (int ct = 0; ct < 4; ++ct) bv[ct] = bias[col0 + ct * 16 + m];
  float csum[4] = {0.f, 0.f, 0.f, 0.f}, csq[4] = {0.f, 0.f, 0.f, 0.f};
  int ntiles = M >> 4;
  int t = blockIdx.x;
  bf16x8 af[8];
  if (t < ntiles) {
    const ushort_t* Ap = A + (size_t)(t * 16 + m) * HID + quad * 8;
#pragma unroll
    for (int kt = 0; kt < 8; ++kt) af[kt] = *(const bf16x8*)(Ap + kt * 32);
  }
  for (; t < ntiles; t += gridDim.x) {
    int tn = t + gridDim.x;
    bf16x8 afn[8];
    if (tn < ntiles) {
      const ushort_t* Ap = A + (size_t)(tn * 16 + m) * HID + quad * 8;
#pragma unroll
      for (int kt = 0; kt < 8; ++kt) afn[kt] = *(const bf16x8*)(Ap + kt * 32);
    }
    f32x4 acc[4];
#pragma unroll
    for (int ct = 0; ct < 4; ++ct) acc[ct] = (f32x4){0.f, 0.f, 0.f, 0.f};
#pragma unroll
    for (int kt = 0; kt < 8; ++kt) {
#pragma unroll
      for (int ct = 0; ct < 4; ++ct)
        acc[ct] = __builtin_amdgcn_mfma_f32_16x16x32_bf16(af[kt], bfrag[ct][kt], acc[ct], 0, 0, 0);
    }
    int rb = t * 16 + quad * 4;
#pragma unroll
    for (int ct = 0; ct < 4; ++ct) {
      int col = col0 + ct * 16 + m;
#pragma unroll
      for (int reg = 0; reg < 4; ++reg) {
        float o = acc[ct][reg] + bv[ct];
        if (DO_RELU) o = fmaxf(o, 0.f);
        out[(size_t)(rb + reg) * HID + col] = f2bf(o);
        if (STATS) { csum[ct] += o; csq[ct] = fmaf(o, o, csq[ct]); }
      }
    }
#pragma unroll
    for (int kt = 0; kt < 8; ++kt) af[kt] = afn[kt];
  }
  if (STATS) {
#pragma unroll
    for (int ct = 0; ct < 4; ++ct) {
      float s = csum[ct], q = csq[ct];
      s += __shfl_xor(s, 16); s += __shfl_xor(s, 32);
      q += __shfl_xor(q, 16); q += __shfl_xor(q, 32);
      if (quad == 0) {
        unsafeAtomicAdd(&stats[col0 + ct * 16 + m], s);
        unsafeAtomicAdd(&stats[HID + col0 + ct * 16 + m], q);
      }
    }
  }
}

// h(bf16) = relu(z*scale + shift) + h ; scale/shift computed from raw stats
__global__ __launch_bounds__(256) void k_bn_apply(const ushort_t* __restrict__ z,
    const float* __restrict__ stats, const float* __restrict__ g,
    const float* __restrict__ b, ushort_t* __restrict__ h, int total4)
{
  int idx = blockIdx.x * 256 + threadIdx.x;
  if (idx >= total4) return;
  int col = (idx & 63) * 4;
  const float inv_n = 1.f / (float)N_NODES;
  float sc[4], sh[4];
#pragma unroll
  for (int c = 0; c < 4; ++c) {
    float mu = stats[col + c] * inv_n;
    float var = stats[HID + col + c] * inv_n - mu * mu;
    float rs = rsqrtf(var + 1e-5f);
    sc[c] = g[col + c] * rs;
    sh[c] = b[col + c] - mu * sc[c];
  }
  ushort4 zv = *(const ushort4*)(z + (size_t)idx * 4);
  ushort4 hv = *(const ushort4*)(h + (size_t)idx * 4);
  float o0 = fmaxf(fmaf(bf2f(zv.x), sc[0], sh[0]), 0.f) + bf2f(hv.x);
  float o1 = fmaxf(fmaf(bf2f(zv.y), sc[1], sh[1]), 0.f) + bf2f(hv.y);
  float o2 = fmaxf(fmaf(bf2f(zv.z), sc[2], sh[2]), 0.f) + bf2f(hv.z);
  float o3 = fmaxf(fmaf(bf2f(zv.w), sc[3], sh[3]), 0.f) + bf2f(hv.w);
  *(ushort4*)(h + (size_t)idx * 4) = make_ushort4(f2bf(o0), f2bf(o1), f2bf(o2), f2bf(o3));
}

__device__ __forceinline__ int lbound(const int* __restrict__ b, int n, int key) {
  int lo = 0, hi = n;
  while (lo < hi) {
    int mid = (lo + hi) >> 1;
    if (b[mid] < key) lo = mid + 1; else hi = mid;
  }
  return lo;
}

// pool per graph (batch sorted): gf[g] = [mean | sum | max] as bf16
__global__ __launch_bounds__(256) void k_pool(const ushort_t* __restrict__ h,
    const int* __restrict__ batch, ushort_t* __restrict__ gf)
{
  int g = blockIdx.x, j = threadIdx.x;
  int lo = lbound(batch, N_NODES, g);
  int hi = lbound(batch, N_NODES, g + 1);
  float s = 0.f, mx = 0.f;  // h >= 0 by construction
  int i = lo;
  for (; i + 1 < hi; i += 2) {
    float v0 = bf2f(h[(size_t)i * HID + j]);
    float v1 = bf2f(h[(size_t)(i + 1) * HID + j]);
    s += v0 + v1; mx = fmaxf(mx, fmaxf(v0, v1));
  }
  if (i < hi) {
    float v = bf2f(h[(size_t)i * HID + j]);
    s += v; mx = fmaxf(mx, v);
  }
  float cntv = fmaxf((float)(hi - lo), 1.f);
  size_t base = (size_t)g * 768;
  gf[base + j] = f2bf(s / cntv);
  gf[base + 256 + j] = f2bf(s);
  gf[base + 512 + j] = f2bf(mx);
}

// small B-in-registers MFMA GEMM for the head: out[M,N] = A[M,K] @ Bt^T + bias
template<int KT, int DO_RELU>
__global__ __launch_bounds__(256, 1) void k_head_gemm(const ushort_t* __restrict__ A,
    const ushort_t* __restrict__ Bt, const float* __restrict__ bias,
    ushort_t* __restrict__ out, int M, int N)
{
  const int K = KT * 32;
  int tid = threadIdx.x;
  int wave = tid >> 6, lane = tid & 63;
  int m = lane & 15, quad = lane >> 4;
  int col = (blockIdx.y * 4 + wave) * 16 + m;
  bf16x8 bfrag[KT];
#pragma unroll
  for (int kt = 0; kt < KT; ++kt)
    bfrag[kt] = *(const bf16x8*)(Bt + (size_t)col * K + kt * 32 + quad * 8);
  float bv = bias[col];
  int ntiles = M >> 4;
  for (int t = blockIdx.x; t < ntiles; t += gridDim.x) {
    const ushort_t* Ap = A + (size_t)(t * 16 + m) * K + quad * 8;
    bf16x8 af[KT];
#pragma unroll
    for (int kt = 0; kt < KT; ++kt) af[kt] = *(const bf16x8*)(Ap + kt * 32);
    f32x4 acc = (f32x4){0.f, 0.f, 0.f, 0.f};
#pragma unroll
    for (int kt = 0; kt < KT; ++kt)
      acc = __builtin_amdgcn_mfma_f32_16x16x32_bf16(af[kt], bfrag[kt], acc, 0, 0, 0);
    int rb = t * 16 + quad * 4;
#pragma unroll
    for (int reg = 0; reg < 4; ++reg) {
      float o = acc[reg] + bv;
      if (DO_RELU) o = fmaxf(o, 0.f);
      out[(size_t)(rb + reg) * N + col] = f2bf(o);
    }
  }
}

// out[g] = dot(g2[g], W3) + b3; one wave per graph
__global__ __launch_bounds__(256) void k_head_out(const ushort_t* __restrict__ g2,
    const float* __restrict__ W3, const float* __restrict__ b3,
    float* __restrict__ out)
{
  int wave = threadIdx.x >> 6, lane = threadIdx.x & 63;
  int g = blockIdx.x * 4 + wave;
  ushort2 v = *(const ushort2*)&g2[(size_t)g * 128 + lane * 2];
  float p = bf2f(v.x) * W3[lane * 2] + bf2f(v.y) * W3[lane * 2 + 1];
#pragma unroll
  for (int off = 32; off > 0; off >>= 1) p += __shfl_down(p, off);
  if (lane == 0) out[g] = p + b3[0];
}

extern "C" void kernel_launch(void* const* d_in, const int* in_sizes, int n_in,
                              void* d_out, int out_size, void* d_ws, size_t ws_size,
                              hipStream_t stream)
{
  const float* x     = (const float*)d_in[0];
  const int*   ei    = (const int*)d_in[1];
  const float* ea    = (const float*)d_in[2];
  const int*   batch = (const int*)d_in[3];
  const float* encW  = (const float*)d_in[4];
  const float* encB  = (const float*)d_in[5];
  const float* edgeW = (const float*)d_in[6];
  const float* edgeB = (const float*)d_in[7];
  const float* W1    = (const float*)d_in[8];
  const float* b1    = (const float*)d_in[9];
  const float* W2    = (const float*)d_in[10];
  const float* b2    = (const float*)d_in[11];
  const float* bng   = (const float*)d_in[12];
  const float* bnb   = (const float*)d_in[13];
  const float* hW1   = (const float*)d_in[14];
  const float* hb1   = (const float*)d_in[15];
  const float* hW2   = (const float*)d_in[16];
  const float* hb2   = (const float*)d_in[17];
  const float* hW3   = (const float*)d_in[18];
  const float* hb3   = (const float*)d_in[19];
  float* out = (float*)d_out;

  const size_t NH = (size_t)N_NODES * HID;
  char* base = (char*)d_ws;
  auto alloc = [&](size_t bytes) -> char* {
    char* p = base; base += (bytes + 63) & ~(size_t)63; return p;
  };
  float*    stats = (float*)alloc(512 * 4);
  int*      offs  = (int*)alloc(50001 * 4);
  int2*     epair = (int2*)alloc((size_t)N_EDGES * 8);
  ushort_t* Wt1   = (ushort_t*)alloc((size_t)NLAYERS * HID * HID * 2);
  ushort_t* Wt2   = (ushort_t*)alloc((size_t)NLAYERS * HID * HID * 2);
  ushort_t* hW1t  = (ushort_t*)alloc((size_t)768 * 256 * 2);
  ushort_t* hW2t  = (ushort_t*)alloc((size_t)256 * 128 * 2);
  ushort_t* gf    = (ushort_t*)alloc((size_t)G_GRAPHS * 768 * 2);
  ushort_t* g1    = (ushort_t*)alloc((size_t)G_GRAPHS * 256 * 2);
  ushort_t* g2    = (ushort_t*)alloc((size_t)G_GRAPHS * 128 * 2);
  ushort_t* zin   = (ushort_t*)alloc(NH * 2);  // also reused as z2
  ushort_t* z1    = (ushort_t*)alloc(NH * 2);
  ushort_t* h     = (ushort_t*)alloc(NH * 2);
  // total ~84 MB

  const int* src = ei;
  const int* dst = ei + N_EDGES;

  // setup: CSR build + weight prep (once per call)
  hipMemsetAsync(offs, 0, 50001 * sizeof(int), stream);
  k_hist<<<(N_EDGES + 255) / 256, 256, 0, stream>>>(dst, offs, N_EDGES);
  k_scan<<<1, 1024, 0, stream>>>(offs, N_NODES);
  k_fill<<<(N_EDGES + 255) / 256, 256, 0, stream>>>(src, dst, offs, epair, N_EDGES);
  k_prep<<<dim3(16, NLAYERS), 256, 0, stream>>>(W1, Wt1);
  k_prep<<<dim3(16, NLAYERS), 256, 0, stream>>>(W2, Wt2);
  k_prept<<<(768 * 256 + 255) / 256, 256, 0, stream>>>(hW1, hW1t, 768, 256);
  k_prept<<<(256 * 128 + 255) / 256, 256, 0, stream>>>(hW2, hW2t, 256, 128);

  k_encoder<<<(N_NODES + 7) / 8, 256, 0, stream>>>(x, encW, encB, h, N_NODES);

  const int GBLK = 512;  // 2 blocks/CU, grid-stride over 3125 row-tiles
  for (int l = 0; l < NLAYERS; ++l) {
    k_gather<<<N_NODES / 4, 256, 0, stream>>>(
        h, ea, offs, epair, edgeW + (size_t)l * 5 * HID, edgeB + (size_t)l * HID,
        zin, stats, N_NODES);
    k_gemm_breg<1, 0><<<GBLK, 256, 0, stream>>>(
        zin, Wt1 + (size_t)l * HID * HID, b1 + (size_t)l * HID, z1, nullptr, N_NODES);
    k_gemm_breg<0, 1><<<GBLK, 256, 0, stream>>>(
        z1, Wt2 + (size_t)l * HID * HID, b2 + (size_t)l * HID, zin, stats, N_NODES);
    k_bn_apply<<<(N_NODES * HID / 4 + 255) / 256, 256, 0, stream>>>(
        zin, stats, bng + (size_t)l * HID, bnb + (size_t)l * HID, h, N_NODES * HID / 4);
  }

  k_pool<<<G_GRAPHS, 256, 0, stream>>>(h, batch, gf);
  k_head_gemm<24, 1><<<dim3(16, 4), 256, 0, stream>>>(gf, hW1t, hb1, g1, G_GRAPHS, 256);
  k_head_gemm<8, 1><<<dim3(16, 2), 256, 0, stream>>>(g1, hW2t, hb2, g2, G_GRAPHS, 128);
  k_head_out<<<G_GRAPHS / 4, 256, 0, stream>>>(g2, hW3, hb3, out);
}